// Round 6
// baseline (2811.016 us; speedup 1.0000x reference)
//
#include <hip/hip_runtime.h>
#include <hip/hip_bf16.h>

typedef __hip_bfloat16 bf16;
__device__ __forceinline__ float b2f(bf16 v){ return __bfloat162float(v); }
__device__ __forceinline__ bf16 f2b(float v){ return __float2bfloat16(v); }
__device__ __forceinline__ void stv(float* p, long i, float v){ p[i] = v; }
__device__ __forceinline__ void stv(bf16*  p, long i, float v){ p[i] = f2b(v); }

// Problem constants
#define BB   8
#define NN   2048
#define DIM  512
#define HID  2048
#define DQK  128
#define GRP  256
#define NG   8            // groups per batch = NN/GRP
#define KW   17           // dw conv taps

// ---------------- LayerNorm (optionally with token-shift of first D/2 channels) ----------
// Inputs fp32 (x) or bf16 (intermediates); output bf16 normalized (affine folded into GEMM).
template<typename TI, int D, int SHIFT_HALF>
__global__ __launch_bounds__(256) void ln_kernel(const TI* __restrict__ in,
                                                 bf16* __restrict__ out)
{
    int row = blockIdx.x;             // [0, rows)
    int t = row % NN;
    int tid = threadIdx.x;
    const int PT = D / 256;
    float vals[PT];
    float s = 0.f, ss = 0.f;
    for (int i = 0; i < PT; i++) {
        int c = tid + i * 256;
        float v;
        if (SHIFT_HALF && c < D / 2) {
            v = (t > 0) ? (float)(in[((long)row - 1) * D + c]) : 0.f;
        } else {
            v = (float)(in[(long)row * D + c]);
        }
        vals[i] = v; s += v; ss += v * v;
    }
    for (int o = 32; o > 0; o >>= 1) { s += __shfl_down(s, o); ss += __shfl_down(ss, o); }
    __shared__ float sm[4], sm2[4];
    int wid = tid >> 6, lane = tid & 63;
    if (lane == 0) { sm[wid] = s; sm2[wid] = ss; }
    __syncthreads();
    if (tid == 0) {
        float a = 0.f, q = 0.f;
        for (int w = 0; w < 4; w++) { a += sm[w]; q += sm2[w]; }
        sm[0] = a; sm2[0] = q;
    }
    __syncthreads();
    float mean = sm[0] / D;
    float var  = fmaxf(sm2[0] / D - mean * mean, 0.f);
    float rs = rsqrtf(var + 1e-5f);
    for (int i = 0; i < PT; i++) {
        int c = tid + i * 256;
        out[(long)row * D + c] = f2b((vals[i] - mean) * rs);
    }
}

// bf16-input LN (no shift) for the 1024-wide second LN
template<int D>
__global__ __launch_bounds__(256) void ln_kernel_bf(const bf16* __restrict__ in,
                                                    bf16* __restrict__ out)
{
    int row = blockIdx.x;
    int tid = threadIdx.x;
    const int PT = D / 256;
    float vals[PT];
    float s = 0.f, ss = 0.f;
    for (int i = 0; i < PT; i++) {
        int c = tid + i * 256;
        float v = b2f(in[(long)row * D + c]);
        vals[i] = v; s += v; ss += v * v;
    }
    for (int o = 32; o > 0; o >>= 1) { s += __shfl_down(s, o); ss += __shfl_down(ss, o); }
    __shared__ float sm[4], sm2[4];
    int wid = tid >> 6, lane = tid & 63;
    if (lane == 0) { sm[wid] = s; sm2[wid] = ss; }
    __syncthreads();
    if (tid == 0) {
        float a = 0.f, q = 0.f;
        for (int w = 0; w < 4; w++) { a += sm[w]; q += sm2[w]; }
        sm[0] = a; sm2[0] = q;
    }
    __syncthreads();
    float mean = sm[0] / D;
    float var  = fmaxf(sm2[0] / D - mean * mean, 0.f);
    float rs = rsqrtf(var + 1e-5f);
    for (int i = 0; i < PT; i++) {
        int c = tid + i * 256;
        out[(long)row * D + c] = f2b((vals[i] - mean) * rs);
    }
}

// ---------------- Generic GEMM: C = silu(affine(A) @ B + bias) ----------------
// A [M,K] bf16 (normalized rows; per-k affine on load), B [K,N] fp32 weights, C bf16.
#define TM 64
#define TN 64
#define TK 32
__global__ __launch_bounds__(256) void gemm_affine_silu(
    const bf16* __restrict__ A, const float* __restrict__ B,
    const float* __restrict__ g, const float* __restrict__ bta,
    const float* __restrict__ bias,
    bf16* __restrict__ C, int M, int N, int Kd, int do_silu)
{
    __shared__ float As[TK][TM + 1];
    __shared__ float Bs[TK][TN + 1];
    int m0 = blockIdx.y * TM, n0 = blockIdx.x * TN;
    int tid = threadIdx.x;
    int tx = tid & 15, ty = tid >> 4;
    float acc[4][4] = {};
    for (int k0 = 0; k0 < Kd; k0 += TK) {
        {
            int kk = tid & (TK - 1);
            int mb = tid / TK;                 // 0..7
            float gv = g[k0 + kk], bv = bta[k0 + kk];
            for (int l = 0; l < 8; l++) {
                int m = mb + l * 8;
                As[kk][m] = b2f(A[(long)(m0 + m) * Kd + k0 + kk]) * gv + bv;
            }
        }
        {
            int nn = tid & 63;
            int kb = tid >> 6;                 // 0..3
            for (int l = 0; l < 8; l++) {
                int kk = kb + l * 4;
                Bs[kk][nn] = B[(long)(k0 + kk) * N + n0 + nn];
            }
        }
        __syncthreads();
        for (int kk = 0; kk < TK; kk++) {
            float av[4], bv[4];
            for (int i = 0; i < 4; i++) av[i] = As[kk][ty * 4 + i];
            for (int j = 0; j < 4; j++) bv[j] = Bs[kk][tx * 4 + j];
            for (int i = 0; i < 4; i++)
                for (int j = 0; j < 4; j++) acc[i][j] += av[i] * bv[j];
        }
        __syncthreads();
    }
    for (int i = 0; i < 4; i++) {
        int m = m0 + ty * 4 + i;
        for (int j = 0; j < 4; j++) {
            int nn = n0 + tx * 4 + j;
            float v = acc[i][j];
            if (bias) v += bias[nn];
            if (do_silu) v = v / (1.f + __expf(-v));
            C[(long)m * N + nn] = f2b(v);
        }
    }
}

// ---------------- Depthwise conv (K=17, SAME) + residual (+ optional fp32 residual) ----
// dst = src + conv(src) [+ xres]; dst type templated (bf16 intermediate, fp32 final out).
#define CT 64
#define TT 64
template<typename TO>
__global__ __launch_bounds__(256) void dwconv_res(
    const bf16* __restrict__ src, const float* __restrict__ dw,
    const float* __restrict__ xres, TO* __restrict__ dst, int C)
{
    int c0 = blockIdx.x * CT;
    int t0 = blockIdx.y * TT;
    int b  = blockIdx.z;
    __shared__ float s[TT + 16][CT];
    int tid = threadIdx.x;
    int c = tid & (CT - 1);
    int rp = tid / CT;                       // 0..3
    const bf16* base = src + (long)b * NN * C;
    for (int l = 0; l < (TT + 16) / 4; l++) {
        int tt = rp + l * 4;                 // 0..79
        int t = t0 + tt - 8;
        float v = 0.f;
        if (t >= 0 && t < NN) v = b2f(base[(long)t * C + c0 + c]);
        s[tt][c] = v;
    }
    __syncthreads();
    float w[KW];
    for (int k = 0; k < KW; k++) w[k] = dw[k * C + c0 + c];
    for (int l = 0; l < TT / 4; l++) {
        int r = rp + l * 4;                  // 0..63
        float acc = s[r + 8][c];             // residual
        float conv = 0.f;
        for (int k = 0; k < KW; k++) conv += s[r + k][c] * w[k];
        acc += conv;
        long gidx = ((long)b * NN + t0 + r) * C + c0 + c;
        if (xres) acc += xres[gidx];
        stv(dst, gidx, acc);
    }
}

// ---------------- Per-group attention scores: attn = relu(QK^T/g)^2, causal ------------
__global__ __launch_bounds__(256) void attn_score(
    const bf16* __restrict__ qk, const float* __restrict__ gamma,
    const float* __restrict__ beta, float* __restrict__ attn)
{
    int grp = blockIdx.z;
    int bi = blockIdx.y, bj = blockIdx.x;
    __shared__ float Qs[TK][TM + 1];
    __shared__ float Ks[TK][TN + 1];
    const bf16* base = qk + (long)grp * GRP * DQK;
    int tid = threadIdx.x; int tx = tid & 15, ty = tid >> 4;
    float acc[4][4] = {};
    for (int k0 = 0; k0 < DQK; k0 += TK) {
        int kk = tid & (TK - 1);
        int rb = tid / TK;
        float gq = gamma[0 * DQK + k0 + kk], bq = beta[0 * DQK + k0 + kk];
        float gk = gamma[2 * DQK + k0 + kk], bk = beta[2 * DQK + k0 + kk];
        for (int l = 0; l < 8; l++) {
            int r = rb + l * 8;
            Qs[kk][r] = b2f(base[(long)(bi * 64 + r) * DQK + k0 + kk]) * gq + bq;
            Ks[kk][r] = b2f(base[(long)(bj * 64 + r) * DQK + k0 + kk]) * gk + bk;
        }
        __syncthreads();
        for (int k2 = 0; k2 < TK; k2++) {
            float av[4], bv[4];
            for (int i = 0; i < 4; i++) av[i] = Qs[k2][ty * 4 + i];
            for (int j = 0; j < 4; j++) bv[j] = Ks[k2][tx * 4 + j];
            for (int i = 0; i < 4; i++)
                for (int j = 0; j < 4; j++) acc[i][j] += av[i] * bv[j];
        }
        __syncthreads();
    }
    float* out = attn + (long)grp * GRP * GRP;
    for (int i = 0; i < 4; i++) {
        int ii = bi * 64 + ty * 4 + i;
        for (int j = 0; j < 4; j++) {
            int jj = bj * 64 + tx * 4 + j;
            float s = acc[i][j] * (1.f / GRP);
            s = fmaxf(s, 0.f); s = s * s;
            if (jj > ii) s = 0.f;
            out[(long)ii * GRP + jj] = s;
        }
    }
}

// ---------------- Per-group lin_k^T @ [v|u] / g -> linkv [cb,g,128,2048] fp32 ------------
__global__ __launch_bounds__(256) void linkv_kernel(
    const bf16* __restrict__ qk, const bf16* __restrict__ hid,
    const float* __restrict__ gamma, const float* __restrict__ beta,
    float* __restrict__ linkv)
{
    int grp = blockIdx.z;
    int bd = blockIdx.y;                     // 0..1
    int be = blockIdx.x;                     // 0..31
    __shared__ float As[TK][TM + 1];
    __shared__ float Bs[TK][TN + 1];
    const bf16* qb = qk  + (long)grp * GRP * DQK;
    const bf16* hb = hid + (long)grp * GRP * HID;
    int tid = threadIdx.x; int tx = tid & 15, ty = tid >> 4;
    float acc[4][4] = {};
    for (int n0 = 0; n0 < GRP; n0 += TK) {
        {
            int d = tid & 63; int nb = tid >> 6;
            float gl = gamma[3 * DQK + bd * 64 + d];
            float bl = beta[3 * DQK + bd * 64 + d];
            for (int l = 0; l < 8; l++) {
                int nn = nb + l * 4;
                As[nn][d] = b2f(qb[(long)(n0 + nn) * DQK + bd * 64 + d]) * gl + bl;
            }
        }
        {
            int e = tid & 63; int nb = tid >> 6;
            for (int l = 0; l < 8; l++) {
                int nn = nb + l * 4;
                Bs[nn][e] = b2f(hb[(long)(n0 + nn) * HID + be * 64 + e]);
            }
        }
        __syncthreads();
        for (int kk = 0; kk < TK; kk++) {
            float av[4], bv[4];
            for (int i = 0; i < 4; i++) av[i] = As[kk][ty * 4 + i];
            for (int j = 0; j < 4; j++) bv[j] = Bs[kk][tx * 4 + j];
            for (int i = 0; i < 4; i++)
                for (int j = 0; j < 4; j++) acc[i][j] += av[i] * bv[j];
        }
        __syncthreads();
    }
    float* out = linkv + (long)grp * DQK * HID;
    for (int i = 0; i < 4; i++) {
        int d = bd * 64 + ty * 4 + i;
        for (int j = 0; j < 4; j++) {
            int e = be * 64 + tx * 4 + j;
            out[(long)d * HID + e] = acc[i][j] * (1.f / GRP);
        }
    }
}

// ---------------- Exclusive cumsum over group axis (per chunk-batch) ----------------
__global__ void cumsum_kernel(float* __restrict__ linkv)
{
    long idx = (long)blockIdx.x * blockDim.x + threadIdx.x;
    int b = (int)(idx / (DQK * HID));
    long off = idx % (DQK * HID);
    float* p = linkv + (long)b * NG * DQK * HID + off;
    float run = 0.f;
    for (int gi = 0; gi < NG; gi++) {
        float v = p[(long)gi * DQK * HID];
        p[(long)gi * DQK * HID] = run;
        run += v;
    }
}

// ---------------- Fused: att = attn@[v,u] + lin_q@linkv_ex, then gating -----------------
__global__ __launch_bounds__(256) void attn_apply(
    const float* __restrict__ attn, const bf16* __restrict__ hid,
    const bf16* __restrict__ qk, const float* __restrict__ gamma,
    const float* __restrict__ beta, const float* __restrict__ linkv,
    bf16* __restrict__ outg)
{
    int grp = blockIdx.z;
    int bi = blockIdx.y;
    int be = blockIdx.x;
    __shared__ float As[TK][TM + 1];
    __shared__ float Bv[TK][TN + 1];
    __shared__ float Bu[TK][TN + 1];
    const float* ab = attn + (long)grp * GRP * GRP;
    const bf16* hb  = hid + (long)grp * GRP * HID;
    const bf16* qb  = qk  + (long)grp * GRP * DQK;
    const float* lk = linkv + (long)grp * DQK * HID;
    int tid = threadIdx.x; int tx = tid & 15, ty = tid >> 4;
    float accv[4][4] = {}, accu[4][4] = {};
    for (int j0 = 0; j0 < GRP; j0 += TK) {
        {
            int kk = tid & (TK - 1); int rb = tid / TK;
            for (int l = 0; l < 8; l++) {
                int r = rb + l * 8;
                As[kk][r] = ab[(long)(bi * 64 + r) * GRP + j0 + kk];
            }
        }
        {
            int e = tid & 63; int jb = tid >> 6;
            for (int l = 0; l < 8; l++) {
                int jj = jb + l * 4;
                Bv[jj][e] = b2f(hb[(long)(j0 + jj) * HID + be * 64 + e]);
                Bu[jj][e] = b2f(hb[(long)(j0 + jj) * HID + 1024 + be * 64 + e]);
            }
        }
        __syncthreads();
        for (int kk = 0; kk < TK; kk++) {
            float av[4], bv[4], bu[4];
            for (int i = 0; i < 4; i++) av[i] = As[kk][ty * 4 + i];
            for (int j = 0; j < 4; j++) { bv[j] = Bv[kk][tx * 4 + j]; bu[j] = Bu[kk][tx * 4 + j]; }
            for (int i = 0; i < 4; i++)
                for (int j = 0; j < 4; j++) { accv[i][j] += av[i] * bv[j]; accu[i][j] += av[i] * bu[j]; }
        }
        __syncthreads();
    }
    for (int d0 = 0; d0 < DQK; d0 += TK) {
        {
            int kk = tid & (TK - 1); int rb = tid / TK;
            float gq = gamma[1 * DQK + d0 + kk], bq = beta[1 * DQK + d0 + kk];
            for (int l = 0; l < 8; l++) {
                int r = rb + l * 8;
                As[kk][r] = b2f(qb[(long)(bi * 64 + r) * DQK + d0 + kk]) * gq + bq;
            }
        }
        {
            int e = tid & 63; int db = tid >> 6;
            for (int l = 0; l < 8; l++) {
                int dd = db + l * 4;
                Bv[dd][e] = lk[(long)(d0 + dd) * HID + be * 64 + e];
                Bu[dd][e] = lk[(long)(d0 + dd) * HID + 1024 + be * 64 + e];
            }
        }
        __syncthreads();
        for (int kk = 0; kk < TK; kk++) {
            float av[4], bv[4], bu[4];
            for (int i = 0; i < 4; i++) av[i] = As[kk][ty * 4 + i];
            for (int j = 0; j < 4; j++) { bv[j] = Bv[kk][tx * 4 + j]; bu[j] = Bu[kk][tx * 4 + j]; }
            for (int i = 0; i < 4; i++)
                for (int j = 0; j < 4; j++) { accv[i][j] += av[i] * bv[j]; accu[i][j] += av[i] * bu[j]; }
        }
        __syncthreads();
    }
    for (int i = 0; i < 4; i++) {
        int ii = bi * 64 + ty * 4 + i;
        const bf16* hrow = hb + (long)ii * HID;
        bf16* orow = outg + ((long)grp * GRP + ii) * 1024;
        for (int j = 0; j < 4; j++) {
            int e = be * 64 + tx * 4 + j;
            float v = b2f(hrow[e]);
            float u = b2f(hrow[1024 + e]);
            float gate = 1.f / (1.f + __expf(-accv[i][j] * u));
            orow[e] = f2b(accu[i][j] * v * gate);
        }
    }
}

extern "C" void kernel_launch(void* const* d_in, const int* in_sizes, int n_in,
                              void* d_out, int out_size, void* d_ws, size_t ws_size,
                              hipStream_t stream)
{
    // Inputs fp32 (reference setup_inputs), OUTPUT fp32 (reference return dtype).
    const float* x      = (const float*)d_in[0];
    const float* ln_h_g = (const float*)d_in[1];
    const float* ln_h_b = (const float*)d_in[2];
    const float* W_h    = (const float*)d_in[3];
    const float* b_h    = (const float*)d_in[4];
    const float* dw_h   = (const float*)d_in[5];
    const float* ln_qk_g= (const float*)d_in[6];
    const float* ln_qk_b= (const float*)d_in[7];
    const float* W_qk   = (const float*)d_in[8];
    const float* b_qk   = (const float*)d_in[9];
    const float* dw_qk  = (const float*)d_in[10];
    const float* gamma  = (const float*)d_in[11];
    const float* beta   = (const float*)d_in[12];
    const float* ln_o_g = (const float*)d_in[13];
    const float* ln_o_b = (const float*)d_in[14];
    const float* W_o    = (const float*)d_in[15];
    const float* b_o    = (const float*)d_in[16];
    const float* dw_o   = (const float*)d_in[17];
    float* outp = (float*)d_out;

    // ---- pick batch-chunk size CB so the aliased workspace fits ws_size ----
    auto bytes_for = [](int cb) -> size_t {
        size_t rows = (size_t)cb * NN;
        return rows * DIM * 2 + rows * HID * 2 + rows * HID * 2
             + rows * DQK * 2 + rows * DQK * 2 + rows * 1024 * 2;
    };
    int CB = 1;
    if (bytes_for(4) <= ws_size) CB = 4;
    else if (bytes_for(2) <= ws_size) CB = 2;

    const size_t rows = (size_t)CB * NN;
    char* p = (char*)d_ws;
    char* slotA = p;            p += rows * DIM * 2;
    char* slotB = p;            p += rows * HID * 2;
    char* slotC = p;            p += rows * HID * 2;
    char* slotD = p;            p += rows * DQK * 2;
    char* slotE = p;            p += rows * DQK * 2;
    char* slotF = p;

    bf16*  hat1    = (bf16*)slotA;
    float* attn    = (float*)slotA;
    bf16*  fin_pre = (bf16*)slotA;
    bf16*  h       = (bf16*)slotB;
    float* linkv   = (float*)slotB;
    bf16*  hat2    = (bf16*)slotB;
    bf16*  hid     = (bf16*)slotC;
    bf16*  qk_pre  = (bf16*)slotD;
    bf16*  qkb     = (bf16*)slotE;
    bf16*  outg    = (bf16*)slotF;

    for (int b0 = 0; b0 < BB; b0 += CB) {
        const float* xc = x    + (size_t)b0 * NN * DIM;
        float* outc     = outp + (size_t)b0 * NN * DIM;
        int R = CB * NN;

        // 1) LN of token-shifted x -> hat1
        ln_kernel<float, DIM, 1><<<R, 256, 0, stream>>>(xc, hat1);
        // 2) h = silu(affine(hat1) @ W_h + b_h)
        gemm_affine_silu<<<dim3(HID / TN, R / TM), 256, 0, stream>>>(
            hat1, W_h, ln_h_g, ln_h_b, b_h, h, R, HID, DIM, 1);
        // 3) qk_pre = silu(affine(hat1) @ W_qk + b_qk)
        gemm_affine_silu<<<dim3(DQK / TN, R / TM), 256, 0, stream>>>(
            hat1, W_qk, ln_qk_g, ln_qk_b, b_qk, qk_pre, R, DQK, DIM, 1);
        // 4) hid = h + dwconv(h)
        dwconv_res<bf16><<<dim3(HID / CT, NN / TT, CB), 256, 0, stream>>>(h, dw_h, nullptr, hid, HID);
        // 5) qkb = qk_pre + dwconv(qk_pre)
        dwconv_res<bf16><<<dim3(DQK / CT, NN / TT, CB), 256, 0, stream>>>(qk_pre, dw_qk, nullptr, qkb, DQK);
        // 6) quadratic scores -> attn (slotA; hat1 dead)
        attn_score<<<dim3(4, 4, CB * NG), 256, 0, stream>>>(qkb, gamma, beta, attn);
        // 7) linear attention kv -> linkv (slotB; h dead)
        linkv_kernel<<<dim3(HID / TN, DQK / TM, CB * NG), 256, 0, stream>>>(qkb, hid, gamma, beta, linkv);
        // 8) exclusive cumsum over groups (in-place)
        cumsum_kernel<<<(CB * DQK * HID) / 256, 256, 0, stream>>>(linkv);
        // 9) fused apply + gating -> outg
        attn_apply<<<dim3(1024 / TN, 4, CB * NG), 256, 0, stream>>>(attn, hid, qkb, gamma, beta, linkv, outg);
        // 10) LN(outg) -> hat2 (slotB; linkv dead)
        ln_kernel_bf<1024><<<R, 256, 0, stream>>>(outg, hat2);
        // 11) fin_pre = silu(affine(hat2) @ W_o + b_o)  (slotA; attn dead)
        gemm_affine_silu<<<dim3(DIM / TN, R / TM), 256, 0, stream>>>(
            hat2, W_o, ln_o_g, ln_o_b, b_o, fin_pre, R, DIM, 1024, 1);
        // 12) d_out(fp32) = x + fin_pre + dwconv(fin_pre)
        dwconv_res<float><<<dim3(DIM / CT, NN / TT, CB), 256, 0, stream>>>(fin_pre, dw_o, xc, outc, DIM);
    }
}

// Round 7
// 1036.372 us; speedup vs baseline: 2.7124x; 2.7124x over previous
//
#include <hip/hip_runtime.h>
#include <hip/hip_bf16.h>

typedef __hip_bfloat16 bf16;
typedef __attribute__((ext_vector_type(8))) short short8;
typedef __attribute__((ext_vector_type(4))) float float4v;
__device__ __forceinline__ float b2f(bf16 v){ return __bfloat162float(v); }
__device__ __forceinline__ bf16 f2b(float v){ return __float2bfloat16(v); }
__device__ __forceinline__ void stv(float* p, long i, float v){ p[i] = v; }
__device__ __forceinline__ void stv(bf16*  p, long i, float v){ p[i] = f2b(v); }

#define MFMA __builtin_amdgcn_mfma_f32_16x16x32_bf16
#define AS1(p) ((const __attribute__((address_space(1))) void*)(p))
#define AS3(p) ((__attribute__((address_space(3))) void*)(p))

// Problem constants
#define BB   8
#define NN   2048
#define DIM  512
#define HID  2048
#define DQK  128
#define GRP  256
#define NG   8
#define KW   17
#define BK   32

// ---------------- LayerNorm (token-shift variant for x, plain bf16 variant) ------------
template<typename TI, int D, int SHIFT_HALF>
__global__ __launch_bounds__(256) void ln_kernel(const TI* __restrict__ in,
                                                 bf16* __restrict__ out)
{
    int row = blockIdx.x;
    int t = row % NN;
    int tid = threadIdx.x;
    const int PT = D / 256;
    float vals[PT];
    float s = 0.f, ss = 0.f;
    for (int i = 0; i < PT; i++) {
        int c = tid + i * 256;
        float v;
        if (SHIFT_HALF && c < D / 2) {
            v = (t > 0) ? (float)(in[((long)row - 1) * D + c]) : 0.f;
        } else {
            v = (float)(in[(long)row * D + c]);
        }
        vals[i] = v; s += v; ss += v * v;
    }
    for (int o = 32; o > 0; o >>= 1) { s += __shfl_down(s, o); ss += __shfl_down(ss, o); }
    __shared__ float sm[4], sm2[4];
    int wid = tid >> 6, lane = tid & 63;
    if (lane == 0) { sm[wid] = s; sm2[wid] = ss; }
    __syncthreads();
    if (tid == 0) {
        float a = 0.f, q = 0.f;
        for (int w = 0; w < 4; w++) { a += sm[w]; q += sm2[w]; }
        sm[0] = a; sm2[0] = q;
    }
    __syncthreads();
    float mean = sm[0] / D;
    float var  = fmaxf(sm2[0] / D - mean * mean, 0.f);
    float rs = rsqrtf(var + 1e-5f);
    for (int i = 0; i < PT; i++) {
        int c = tid + i * 256;
        out[(long)row * D + c] = f2b((vals[i] - mean) * rs);
    }
}

template<int D>
__global__ __launch_bounds__(256) void ln_kernel_bf(const bf16* __restrict__ in,
                                                    bf16* __restrict__ out)
{
    int row = blockIdx.x;
    int tid = threadIdx.x;
    const int PT = D / 256;
    float vals[PT];
    float s = 0.f, ss = 0.f;
    for (int i = 0; i < PT; i++) {
        int c = tid + i * 256;
        float v = b2f(in[(long)row * D + c]);
        vals[i] = v; s += v; ss += v * v;
    }
    for (int o = 32; o > 0; o >>= 1) { s += __shfl_down(s, o); ss += __shfl_down(ss, o); }
    __shared__ float sm[4], sm2[4];
    int wid = tid >> 6, lane = tid & 63;
    if (lane == 0) { sm[wid] = s; sm2[wid] = ss; }
    __syncthreads();
    if (tid == 0) {
        float a = 0.f, q = 0.f;
        for (int w = 0; w < 4; w++) { a += sm[w]; q += sm2[w]; }
        sm[0] = a; sm2[0] = q;
    }
    __syncthreads();
    float mean = sm[0] / D;
    float var  = fmaxf(sm2[0] / D - mean * mean, 0.f);
    float rs = rsqrtf(var + 1e-5f);
    for (int i = 0; i < PT; i++) {
        int c = tid + i * 256;
        out[(long)row * D + c] = f2b((vals[i] - mean) * rs);
    }
}

// ---------------- weight prep: WT[n][k] = bf16(g[k]*W[k][n]) -----------------------------
__global__ __launch_bounds__(256) void prep_wT(const float* __restrict__ W,
                                               const float* __restrict__ g,
                                               bf16* __restrict__ WT, int K, int N)
{
    int k0 = blockIdx.x * 32, n0 = blockIdx.y * 32;
    __shared__ float Ws[32][33];
    int tid = threadIdx.x;
    for (int l = 0; l < 4; l++) {
        int e = tid + 256 * l;
        int kk = e >> 5, nn = e & 31;
        Ws[kk][nn] = g[k0 + kk] * W[(size_t)(k0 + kk) * N + n0 + nn];
    }
    __syncthreads();
    for (int l = 0; l < 4; l++) {
        int e = tid + 256 * l;
        int nn = e >> 5, kk = e & 31;
        WT[(size_t)(n0 + nn) * K + k0 + kk] = f2b(Ws[kk][nn]);
    }
}

// bias'[n] = b[n] + sum_k lnb[k]*W[k][n]
__global__ __launch_bounds__(256) void prep_bias(const float* __restrict__ W,
                                                 const float* __restrict__ lnb,
                                                 const float* __restrict__ b,
                                                 float* __restrict__ out, int K, int N)
{
    int n = blockIdx.x * 256 + threadIdx.x;
    if (n >= N) return;
    float s = b[n];
    for (int k = 0; k < K; k++) s += lnb[k] * W[(size_t)k * N + n];
    out[n] = s;
}

// ---------------- staging helper: 128 rows x 32 cols bf16 tile via global_load_lds -------
__device__ __forceinline__ void stage_tile(const bf16* base, size_t ld, bf16* dst,
                                           int wave, int lane)
{
    int lrow = lane >> 2, lcol = lane & 3;
    for (int cc = 0; cc < 2; cc++) {
        int c = wave * 2 + cc;
        int row = c * 16 + lrow;
        const bf16* g = base + (size_t)row * ld + lcol * 8;
        __builtin_amdgcn_global_load_lds(AS1(g), AS3(dst + c * 512), 16, 0, 0);
    }
}

// ---------------- MFMA GEMM: C[m][n] = silu(A@B^T + bias) -------------------------------
// A [M][K] bf16 row-major; BT [N][K] bf16 row-major; 128x128 block tiles; 256 threads.
__global__ __launch_bounds__(256) void gemm_mfma(
    const bf16* __restrict__ A, const bf16* __restrict__ BT,
    const float* __restrict__ bias, bf16* __restrict__ C,
    int M, int N, int K)
{
    __shared__ bf16 As[128 * BK];
    __shared__ bf16 Bs[128 * BK];
    int n0 = blockIdx.x * 128, m0 = blockIdx.y * 128;
    int tid = threadIdx.x, wave = tid >> 6, lane = tid & 63;
    int wm = wave & 1, wn = wave >> 1;
    float4v acc[4][4] = {};
    for (int k0 = 0; k0 < K; k0 += BK) {
        stage_tile(A  + (size_t)m0 * K + k0, K, As, wave, lane);
        stage_tile(BT + (size_t)n0 * K + k0, K, Bs, wave, lane);
        __syncthreads();
        int col = lane & 15, quad = lane >> 4;
        short8 a[4], b[4];
        for (int t = 0; t < 4; t++) {
            a[t] = *(const short8*)(As + (wm * 64 + t * 16 + col) * BK + quad * 8);
            b[t] = *(const short8*)(Bs + (wn * 64 + t * 16 + col) * BK + quad * 8);
        }
        for (int i = 0; i < 4; i++)
            for (int j = 0; j < 4; j++)
                acc[i][j] = MFMA(a[i], b[j], acc[i][j], 0, 0, 0);
        __syncthreads();
    }
    int col = lane & 15, quad = lane >> 4;
    for (int i = 0; i < 4; i++) {
        for (int j = 0; j < 4; j++) {
            int n = n0 + wn * 64 + j * 16 + col;
            float bs = bias[n];
            for (int r = 0; r < 4; r++) {
                int m = m0 + wm * 64 + i * 16 + quad * 4 + r;
                float v = acc[i][j][r] + bs;
                v = v / (1.f + __expf(-v));
                C[(size_t)m * N + n] = f2b(v);
            }
        }
    }
}

// ---------------- attn scores MFMA: P = relu(QK^T/256)^2, causal, bf16 ------------------
__global__ __launch_bounds__(256) void attn_score_mfma(
    const bf16* __restrict__ quadq, const bf16* __restrict__ quadk,
    bf16* __restrict__ P)
{
    int g = blockIdx.z, bi = blockIdx.y, bj = blockIdx.x;
    bf16* Pg = P + (size_t)g * GRP * GRP;
    int tid = threadIdx.x;
    if (bj > bi) {   // fully masked tile: write zeros
        short8 z = {};
        int rr = tid >> 1, half = tid & 1;
        short* dst = (short*)Pg + (size_t)(bi * 128 + rr) * GRP + bj * 128 + half * 64;
        for (int q = 0; q < 8; q++) ((short8*)dst)[q] = z;
        return;
    }
    __shared__ bf16 As[128 * BK];
    __shared__ bf16 Bs[128 * BK];
    int wave = tid >> 6, lane = tid & 63;
    int wm = wave & 1, wn = wave >> 1;
    float4v acc[4][4] = {};
    const bf16* Ab = quadq + (size_t)(g * GRP + bi * 128) * DQK;
    const bf16* Bb = quadk + (size_t)(g * GRP + bj * 128) * DQK;
    for (int k0 = 0; k0 < DQK; k0 += BK) {
        stage_tile(Ab + k0, DQK, As, wave, lane);
        stage_tile(Bb + k0, DQK, Bs, wave, lane);
        __syncthreads();
        int col = lane & 15, quad = lane >> 4;
        short8 a[4], b[4];
        for (int t = 0; t < 4; t++) {
            a[t] = *(const short8*)(As + (wm * 64 + t * 16 + col) * BK + quad * 8);
            b[t] = *(const short8*)(Bs + (wn * 64 + t * 16 + col) * BK + quad * 8);
        }
        for (int i = 0; i < 4; i++)
            for (int j = 0; j < 4; j++)
                acc[i][j] = MFMA(a[i], b[j], acc[i][j], 0, 0, 0);
        __syncthreads();
    }
    int col = lane & 15, quad = lane >> 4;
    for (int i = 0; i < 4; i++) {
        for (int j = 0; j < 4; j++) {
            int jj = bj * 128 + wn * 64 + j * 16 + col;
            for (int r = 0; r < 4; r++) {
                int ii = bi * 128 + wm * 64 + i * 16 + quad * 4 + r;
                float s = acc[i][j][r] * (1.f / GRP);
                s = fmaxf(s, 0.f); s = s * s;
                if (jj > ii) s = 0.f;
                Pg[(size_t)ii * GRP + jj] = f2b(s);
            }
        }
    }
}

// ---------------- linkv MFMA: linkvT[g][e][d] = (hidT_g @ linkT_g^T)/256 ----------------
// A rows: hidT[e0+row][g*256+k]; B rows: linkT[d][g*256+k]; M=2048(e) N=128(d) K=256.
__global__ __launch_bounds__(256) void linkv_mfma(
    const bf16* __restrict__ hidT, const bf16* __restrict__ linkT,
    float* __restrict__ linkvT, int rowsC)
{
    int g = blockIdx.z, eb = blockIdx.y;
    int e0 = eb * 128;
    __shared__ bf16 As[128 * BK];
    __shared__ bf16 Bs[128 * BK];
    int tid = threadIdx.x, wave = tid >> 6, lane = tid & 63;
    int wm = wave & 1, wn = wave >> 1;
    float4v acc[4][4] = {};
    for (int k0 = 0; k0 < GRP; k0 += BK) {
        stage_tile(hidT  + (size_t)e0 * rowsC + g * GRP + k0, rowsC, As, wave, lane);
        stage_tile(linkT + (size_t)0  * rowsC + g * GRP + k0, rowsC, Bs, wave, lane);
        __syncthreads();
        int col = lane & 15, quad = lane >> 4;
        short8 a[4], b[4];
        for (int t = 0; t < 4; t++) {
            a[t] = *(const short8*)(As + (wm * 64 + t * 16 + col) * BK + quad * 8);
            b[t] = *(const short8*)(Bs + (wn * 64 + t * 16 + col) * BK + quad * 8);
        }
        for (int i = 0; i < 4; i++)
            for (int j = 0; j < 4; j++)
                acc[i][j] = MFMA(a[i], b[j], acc[i][j], 0, 0, 0);
        __syncthreads();
    }
    float* out = linkvT + (size_t)g * (HID * DQK);
    int col = lane & 15, quad = lane >> 4;
    for (int i = 0; i < 4; i++) {
        for (int j = 0; j < 4; j++) {
            int d = wn * 64 + j * 16 + col;
            for (int r = 0; r < 4; r++) {
                int e = e0 + wm * 64 + i * 16 + quad * 4 + r;
                out[(size_t)e * DQK + d] = acc[i][j][r] * (1.f / GRP);
            }
        }
    }
}

// ---------------- exclusive cumsum over group axis ---------------------------------------
__global__ void cumsum_kernel(float* __restrict__ linkv)
{
    long idx = (long)blockIdx.x * blockDim.x + threadIdx.x;   // over cb*HID*DQK
    int b = (int)(idx / (DQK * HID));
    long off = idx % (DQK * HID);
    float* p = linkv + (long)b * NG * DQK * HID + off;
    float run = 0.f;
    for (int gi = 0; gi < NG; gi++) {
        float v = p[(long)gi * DQK * HID];
        p[(long)gi * DQK * HID] = run;
        run += v;
    }
}

// ---------------- fused attn apply MFMA + gating -----------------------------------------
// Block: 128 tokens (mb) x 64 e-pairs (e0): cols 0..63 -> att_v(e0+), 64..127 -> att_u.
__global__ __launch_bounds__(256) void attn_apply_mfma(
    const bf16* __restrict__ P, const bf16* __restrict__ hidT,
    const bf16* __restrict__ linq, const float* __restrict__ linkvT,
    const bf16* __restrict__ hid, bf16* __restrict__ outg, int rowsC)
{
    int g = blockIdx.z, mb = blockIdx.y, e0 = blockIdx.x * 64;
    __shared__ bf16 As[128 * BK];
    __shared__ bf16 Bs[128 * BK];
    int tid = threadIdx.x, wave = tid >> 6, lane = tid & 63;
    int lrow = lane >> 2, lcol = lane & 3;
    int m0 = mb * 128;
    float4v acc[2][8] = {};
    const bf16* Pg = P + (size_t)g * GRP * GRP;
    // phase 1: quadratic, K = 256 over j
    for (int j0 = 0; j0 < GRP; j0 += BK) {
        for (int cc = 0; cc < 2; cc++) {
            int c = wave * 2 + cc;
            int row = c * 16 + lrow;
            const bf16* ga = Pg + (size_t)(m0 + row) * GRP + j0 + lcol * 8;
            __builtin_amdgcn_global_load_lds(AS1(ga), AS3(As + c * 512), 16, 0, 0);
            int er = (c < 4) ? (e0 + row) : (1024 + e0 + (row - 64));
            const bf16* gb = hidT + (size_t)er * rowsC + g * GRP + j0 + lcol * 8;
            __builtin_amdgcn_global_load_lds(AS1(gb), AS3(Bs + c * 512), 16, 0, 0);
        }
        __syncthreads();
        int col = lane & 15, quad = lane >> 4;
        short8 a[2], b[8];
        for (int t = 0; t < 2; t++)
            a[t] = *(const short8*)(As + (wave * 32 + t * 16 + col) * BK + quad * 8);
        for (int t = 0; t < 8; t++)
            b[t] = *(const short8*)(Bs + (t * 16 + col) * BK + quad * 8);
        for (int i = 0; i < 2; i++)
            for (int j = 0; j < 8; j++)
                acc[i][j] = MFMA(a[i], b[j], acc[i][j], 0, 0, 0);
        __syncthreads();
    }
    // phase 2: linear, K = 128 over d
    const float* Lg = linkvT + (size_t)g * (HID * DQK);
    for (int d0 = 0; d0 < DQK; d0 += BK) {
        for (int cc = 0; cc < 2; cc++) {
            int c = wave * 2 + cc;
            int row = c * 16 + lrow;
            const bf16* ga = linq + (size_t)(g * GRP + m0 + row) * DQK + d0 + lcol * 8;
            __builtin_amdgcn_global_load_lds(AS1(ga), AS3(As + c * 512), 16, 0, 0);
        }
        {   // manual B staging: fp32 linkvT -> bf16 LDS
            int rr = tid >> 1, half = tid & 1;
            int er = (rr < 64) ? (e0 + rr) : (1024 + e0 + (rr - 64));
            const float* src = Lg + (size_t)er * DQK + d0 + half * 16;
            bf16* dstp = Bs + rr * BK + half * 16;
            for (int q = 0; q < 4; q++) {
                float4v f = *(const float4v*)(src + q * 4);
                dstp[q * 4 + 0] = f2b(f[0]); dstp[q * 4 + 1] = f2b(f[1]);
                dstp[q * 4 + 2] = f2b(f[2]); dstp[q * 4 + 3] = f2b(f[3]);
            }
        }
        __syncthreads();
        int col = lane & 15, quad = lane >> 4;
        short8 a[2], b[8];
        for (int t = 0; t < 2; t++)
            a[t] = *(const short8*)(As + (wave * 32 + t * 16 + col) * BK + quad * 8);
        for (int t = 0; t < 8; t++)
            b[t] = *(const short8*)(Bs + (t * 16 + col) * BK + quad * 8);
        for (int i = 0; i < 2; i++)
            for (int j = 0; j < 8; j++)
                acc[i][j] = MFMA(a[i], b[j], acc[i][j], 0, 0, 0);
        __syncthreads();
    }
    // epilogue with gating
    int col = lane & 15, quad = lane >> 4;
    for (int mt = 0; mt < 2; mt++) {
        for (int nt = 0; nt < 4; nt++) {
            for (int r = 0; r < 4; r++) {
                int tokg = g * GRP + m0 + wave * 32 + mt * 16 + quad * 4 + r;
                int e = e0 + nt * 16 + col;
                float av = acc[mt][nt][r];
                float au = acc[mt][nt + 4][r];
                float v = b2f(hid[(size_t)tokg * HID + e]);
                float u = b2f(hid[(size_t)tokg * HID + 1024 + e]);
                float gate = 1.f / (1.f + __expf(-av * u));
                outg[(size_t)tokg * 1024 + e] = f2b(au * v * gate);
            }
        }
    }
}

// ---------------- qk affine split: quadq/quadk/linq natural + linkT transposed -----------
__global__ __launch_bounds__(256) void qk_affine(
    const bf16* __restrict__ qkb, const float* __restrict__ gamma,
    const float* __restrict__ beta,
    bf16* __restrict__ quadq, bf16* __restrict__ quadk,
    bf16* __restrict__ linq, bf16* __restrict__ linkT, int rowsC)
{
    int t0 = blockIdx.x * 64;
    __shared__ bf16 L[64][DQK + 2];
    int tid = threadIdx.x;
    int d = tid & 127, tl = tid >> 7;
    for (int l = 0; l < 32; l++) {
        int tok = t0 + tl + 2 * l;
        float q = b2f(qkb[(size_t)tok * DQK + d]);
        quadq[(size_t)tok * DQK + d] = f2b(q * gamma[0 * DQK + d] + beta[0 * DQK + d]);
        linq [(size_t)tok * DQK + d] = f2b(q * gamma[1 * DQK + d] + beta[1 * DQK + d]);
        quadk[(size_t)tok * DQK + d] = f2b(q * gamma[2 * DQK + d] + beta[2 * DQK + d]);
        L[tok - t0][d] = f2b(q * gamma[3 * DQK + d] + beta[3 * DQK + d]);
    }
    __syncthreads();
    int dd = tid >> 1, half = tid & 1;
    for (int t = 0; t < 32; t++) {
        int tok = half * 32 + t;
        linkT[(size_t)dd * rowsC + t0 + tok] = L[tok][dd];
    }
}

// ---------------- dwconv (generic) + final fp32 variant ----------------------------------
template<typename TO>
__global__ __launch_bounds__(256) void dwconv_res(
    const bf16* __restrict__ src, const float* __restrict__ dw,
    const float* __restrict__ xres, TO* __restrict__ dst, int C)
{
    int c0 = blockIdx.x * 64;
    int t0 = blockIdx.y * 64;
    int b  = blockIdx.z;
    __shared__ float s[80][64];
    int tid = threadIdx.x;
    int c = tid & 63;
    int rp = tid >> 6;
    const bf16* base = src + (size_t)b * NN * C;
    for (int l = 0; l < 20; l++) {
        int tt = rp + l * 4;
        int t = t0 + tt - 8;
        float v = 0.f;
        if (t >= 0 && t < NN) v = b2f(base[(size_t)t * C + c0 + c]);
        s[tt][c] = v;
    }
    __syncthreads();
    float w[KW];
    for (int k = 0; k < KW; k++) w[k] = dw[k * C + c0 + c];
    for (int l = 0; l < 16; l++) {
        int r = rp + l * 4;
        float acc = s[r + 8][c];
        for (int k = 0; k < KW; k++) acc += s[r + k][c] * w[k];
        long gidx = ((long)b * NN + t0 + r) * C + c0 + c;
        if (xres) acc += xres[gidx];
        stv(dst, gidx, acc);
    }
}

// dwconv for h: writes hid [tok][2048] AND hidT [2048][rowsC]
__global__ __launch_bounds__(256) void dwconv_dual(
    const bf16* __restrict__ src, const float* __restrict__ dw,
    bf16* __restrict__ dst, bf16* __restrict__ dstT, int rowsC)
{
    int c0 = blockIdx.x * 64, t0 = blockIdx.y * 64, b = blockIdx.z;
    __shared__ float s[80][64];
    __shared__ bf16 o[64][65];
    int tid = threadIdx.x;
    int c = tid & 63, rp = tid >> 6;
    const bf16* base = src + (size_t)b * NN * HID + c0;
    for (int l = 0; l < 20; l++) {
        int tt = rp + l * 4;
        int t = t0 + tt - 8;
        float v = 0.f;
        if (t >= 0 && t < NN) v = b2f(base[(size_t)t * HID + c]);
        s[tt][c] = v;
    }
    __syncthreads();
    float w[KW];
    for (int k = 0; k < KW; k++) w[k] = dw[k * HID + c0 + c];
    for (int l = 0; l < 16; l++) {
        int r = rp + l * 4;
        float acc = s[r + 8][c];
        for (int k = 0; k < KW; k++) acc += s[r + k][c] * w[k];
        bf16 hv = f2b(acc);
        dst[((size_t)b * NN + t0 + r) * HID + c0 + c] = hv;
        o[c][r] = hv;
    }
    __syncthreads();
    int ch = tid >> 2, seg = tid & 3;
    for (int t = 0; t < 16; t++) {
        int tok = seg * 16 + t;
        dstT[(size_t)(c0 + ch) * rowsC + b * NN + t0 + tok] = o[ch][tok];
    }
}

extern "C" void kernel_launch(void* const* d_in, const int* in_sizes, int n_in,
                              void* d_out, int out_size, void* d_ws, size_t ws_size,
                              hipStream_t stream)
{
    const float* x      = (const float*)d_in[0];
    const float* ln_h_g = (const float*)d_in[1];
    const float* ln_h_b = (const float*)d_in[2];
    const float* W_h    = (const float*)d_in[3];
    const float* b_h    = (const float*)d_in[4];
    const float* dw_h   = (const float*)d_in[5];
    const float* ln_qk_g= (const float*)d_in[6];
    const float* ln_qk_b= (const float*)d_in[7];
    const float* W_qk   = (const float*)d_in[8];
    const float* b_qk   = (const float*)d_in[9];
    const float* dw_qk  = (const float*)d_in[10];
    const float* gamma  = (const float*)d_in[11];
    const float* beta   = (const float*)d_in[12];
    const float* ln_o_g = (const float*)d_in[13];
    const float* ln_o_b = (const float*)d_in[14];
    const float* W_o    = (const float*)d_in[15];
    const float* b_o    = (const float*)d_in[16];
    const float* dw_o   = (const float*)d_in[17];
    float* outp = (float*)d_out;

    // ---- fixed region: transposed/scaled weights + fused biases ----
    char* p = (char*)d_ws;
    bf16* WT_h  = (bf16*)p;  p += (size_t)HID * DIM * 2;        // [2048][512]
    bf16* WT_qk = (bf16*)p;  p += (size_t)DQK * DIM * 2;        // [128][512]
    bf16* WT_o  = (bf16*)p;  p += (size_t)DIM * 1024 * 2;       // [512][1024]
    float* bias_h  = (float*)p; p += HID * 4;
    float* bias_qk = (float*)p; p += DQK * 4;
    float* bias_o  = (float*)p; p += DIM * 4;
    p = (char*)(((uintptr_t)p + 255) & ~(uintptr_t)255);
    size_t fixed = (size_t)(p - (char*)d_ws);

    auto bytes_for = [fixed](int cb) -> size_t {
        size_t rows = (size_t)cb * NN;
        size_t s_big = rows * HID * 2;     // 3x (h/linkvT, hid/hat2, hidT)
        size_t s_out = rows * 1024 * 2;    // outg
        size_t s_hat = rows * DIM * 2;     // hat1/P
        size_t s_qk  = rows * DQK * 2;     // x5
        return fixed + 3 * s_big + s_out + s_hat + 5 * s_qk + 4096;
    };
    int CB = 1;
    if (bytes_for(4) <= ws_size) CB = 4;
    else if (bytes_for(2) <= ws_size) CB = 2;
    const int rowsC = CB * NN;
    const size_t rows = (size_t)rowsC;

    char* s1 = p;               p += rows * HID * 2;   // h -> linkvT -> fin_pre
    char* s2 = p;               p += rows * HID * 2;   // hid -> hat2
    char* s3 = p;               p += rows * HID * 2;   // hidT
    char* s4 = p;               p += rows * 1024 * 2;  // outg
    char* s5 = p;               p += rows * DIM * 2;   // hat1 -> P
    char* s6 = p;               p += rows * DQK * 2;   // qk_pre -> linkT
    char* s7 = p;               p += rows * DQK * 2;   // qkb
    char* s8 = p;               p += rows * DQK * 2;   // quadq
    char* s9 = p;               p += rows * DQK * 2;   // quadk
    char* s10 = p;              p += rows * DQK * 2;   // linq

    bf16*  h       = (bf16*)s1;
    float* linkvT  = (float*)s1;
    bf16*  fin_pre = (bf16*)s1;
    bf16*  hid     = (bf16*)s2;
    bf16*  hat2    = (bf16*)s2;
    bf16*  hidT    = (bf16*)s3;
    bf16*  outg    = (bf16*)s4;
    bf16*  hat1    = (bf16*)s5;
    bf16*  P       = (bf16*)s5;
    bf16*  qk_pre  = (bf16*)s6;
    bf16*  linkT   = (bf16*)s6;
    bf16*  qkb     = (bf16*)s7;
    bf16*  quadq   = (bf16*)s8;
    bf16*  quadk   = (bf16*)s9;
    bf16*  linq    = (bf16*)s10;

    // ---- weight prep (fold LN affine into weights/biases) ----
    prep_wT<<<dim3(DIM / 32, HID / 32), 256, 0, stream>>>(W_h, ln_h_g, WT_h, DIM, HID);
    prep_wT<<<dim3(DIM / 32, DQK / 32), 256, 0, stream>>>(W_qk, ln_qk_g, WT_qk, DIM, DQK);
    prep_wT<<<dim3(1024 / 32, DIM / 32), 256, 0, stream>>>(W_o, ln_o_g, WT_o, 1024, DIM);
    prep_bias<<<HID / 256, 256, 0, stream>>>(W_h, ln_h_b, b_h, bias_h, DIM, HID);
    prep_bias<<<1, 256, 0, stream>>>(W_qk, ln_qk_b, b_qk, bias_qk, DIM, DQK);
    prep_bias<<<2, 256, 0, stream>>>(W_o, ln_o_b, b_o, bias_o, 1024, DIM);

    const int G = CB * NG;   // groups per chunk
    for (int b0 = 0; b0 < BB; b0 += CB) {
        const float* xc = x    + (size_t)b0 * NN * DIM;
        float* outc     = outp + (size_t)b0 * NN * DIM;
        int R = rowsC;

        // 1) LN of token-shifted x -> hat1 (pure normalized; affine folded into WT/bias)
        ln_kernel<float, DIM, 1><<<R, 256, 0, stream>>>(xc, hat1);
        // 2) h = silu(hat1 @ W_h' + bias_h')
        gemm_mfma<<<dim3(HID / 128, R / 128), 256, 0, stream>>>(hat1, WT_h, bias_h, h, R, HID, DIM);
        // 3) qk_pre = silu(hat1 @ W_qk' + bias_qk')
        gemm_mfma<<<dim3(1, R / 128), 256, 0, stream>>>(hat1, WT_qk, bias_qk, qk_pre, R, DQK, DIM);
        // 4) hid + hidT = h + dwconv(h)
        dwconv_dual<<<dim3(HID / 64, NN / 64, CB), 256, 0, stream>>>(h, dw_h, hid, hidT, rowsC);
        // 5) qkb = qk_pre + dwconv(qk_pre)
        dwconv_res<bf16><<<dim3(DQK / 64, NN / 64, CB), 256, 0, stream>>>(qk_pre, dw_qk, nullptr, qkb, DQK);
        // 6) qk affine -> quadq/quadk/linq (natural) + linkT (transposed)
        qk_affine<<<R / 64, 256, 0, stream>>>(qkb, gamma, beta, quadq, quadk, linq, linkT, rowsC);
        // 7) quadratic scores -> P (bf16)
        attn_score_mfma<<<dim3(2, 2, G), 256, 0, stream>>>(quadq, quadk, P);
        // 8) linear attention kv -> linkvT [g][e][d] fp32
        linkv_mfma<<<dim3(1, HID / 128, G), 256, 0, stream>>>(hidT, linkT, linkvT, rowsC);
        // 9) exclusive cumsum over groups (in-place)
        cumsum_kernel<<<(CB * DQK * HID) / 256, 256, 0, stream>>>(linkvT);
        // 10) fused apply + gating -> outg
        attn_apply_mfma<<<dim3(16, 2, G), 256, 0, stream>>>(P, hidT, linq, linkvT, hid, outg, rowsC);
        // 11) LN(outg) -> hat2
        ln_kernel_bf<1024><<<R, 256, 0, stream>>>(outg, hat2);
        // 12) fin_pre = silu(hat2 @ W_o' + bias_o')
        gemm_mfma<<<dim3(DIM / 128, R / 128), 256, 0, stream>>>(hat2, WT_o, bias_o, fin_pre, R, DIM, 1024);
        // 13) d_out(fp32) = x + fin_pre + dwconv(fin_pre)
        dwconv_res<float><<<dim3(DIM / 64, NN / 64, CB), 256, 0, stream>>>(fin_pre, dw_o, xc, outc, DIM);
    }
}

// Round 8
// 612.582 us; speedup vs baseline: 4.5888x; 1.6918x over previous
//
#include <hip/hip_runtime.h>
#include <hip/hip_bf16.h>

typedef __hip_bfloat16 bf16;
typedef __attribute__((ext_vector_type(8))) short short8;
typedef __attribute__((ext_vector_type(4))) float float4v;
__device__ __forceinline__ float b2f(bf16 v){ return __bfloat162float(v); }
__device__ __forceinline__ bf16 f2b(float v){ return __float2bfloat16(v); }
__device__ __forceinline__ void stv(float* p, long i, float v){ p[i] = v; }
__device__ __forceinline__ void stv(bf16*  p, long i, float v){ p[i] = f2b(v); }

#define MFMA __builtin_amdgcn_mfma_f32_16x16x32_bf16
#define AS1(p) ((const __attribute__((address_space(1))) void*)(p))
#define AS3(p) ((__attribute__((address_space(3))) void*)(p))

// Problem constants
#define BB   8
#define NN   2048
#define DIM  512
#define HID  2048
#define DQK  128
#define GRP  256
#define NG   8
#define KW   17
#define BK   32

// ---------------- LayerNorm (token-shift variant for x, plain bf16 variant) ------------
template<typename TI, int D, int SHIFT_HALF>
__global__ __launch_bounds__(256) void ln_kernel(const TI* __restrict__ in,
                                                 bf16* __restrict__ out)
{
    int row = blockIdx.x;
    int t = row % NN;
    int tid = threadIdx.x;
    const int PT = D / 256;
    float vals[PT];
    float s = 0.f, ss = 0.f;
    for (int i = 0; i < PT; i++) {
        int c = tid + i * 256;
        float v;
        if (SHIFT_HALF && c < D / 2) {
            v = (t > 0) ? (float)(in[((long)row - 1) * D + c]) : 0.f;
        } else {
            v = (float)(in[(long)row * D + c]);
        }
        vals[i] = v; s += v; ss += v * v;
    }
    for (int o = 32; o > 0; o >>= 1) { s += __shfl_down(s, o); ss += __shfl_down(ss, o); }
    __shared__ float sm[4], sm2[4];
    int wid = tid >> 6, lane = tid & 63;
    if (lane == 0) { sm[wid] = s; sm2[wid] = ss; }
    __syncthreads();
    if (tid == 0) {
        float a = 0.f, q = 0.f;
        for (int w = 0; w < 4; w++) { a += sm[w]; q += sm2[w]; }
        sm[0] = a; sm2[0] = q;
    }
    __syncthreads();
    float mean = sm[0] / D;
    float var  = fmaxf(sm2[0] / D - mean * mean, 0.f);
    float rs = rsqrtf(var + 1e-5f);
    for (int i = 0; i < PT; i++) {
        int c = tid + i * 256;
        out[(long)row * D + c] = f2b((vals[i] - mean) * rs);
    }
}

template<int D>
__global__ __launch_bounds__(256) void ln_kernel_bf(const bf16* __restrict__ in,
                                                    bf16* __restrict__ out)
{
    int row = blockIdx.x;
    int tid = threadIdx.x;
    const int PT = D / 256;
    float vals[PT];
    float s = 0.f, ss = 0.f;
    for (int i = 0; i < PT; i++) {
        int c = tid + i * 256;
        float v = b2f(in[(long)row * D + c]);
        vals[i] = v; s += v; ss += v * v;
    }
    for (int o = 32; o > 0; o >>= 1) { s += __shfl_down(s, o); ss += __shfl_down(ss, o); }
    __shared__ float sm[4], sm2[4];
    int wid = tid >> 6, lane = tid & 63;
    if (lane == 0) { sm[wid] = s; sm2[wid] = ss; }
    __syncthreads();
    if (tid == 0) {
        float a = 0.f, q = 0.f;
        for (int w = 0; w < 4; w++) { a += sm[w]; q += sm2[w]; }
        sm[0] = a; sm2[0] = q;
    }
    __syncthreads();
    float mean = sm[0] / D;
    float var  = fmaxf(sm2[0] / D - mean * mean, 0.f);
    float rs = rsqrtf(var + 1e-5f);
    for (int i = 0; i < PT; i++) {
        int c = tid + i * 256;
        out[(long)row * D + c] = f2b((vals[i] - mean) * rs);
    }
}

// ---------------- weight prep: WT[n][k] = bf16(g[k]*W[k][n]) -----------------------------
__global__ __launch_bounds__(256) void prep_wT(const float* __restrict__ W,
                                               const float* __restrict__ g,
                                               bf16* __restrict__ WT, int K, int N)
{
    int k0 = blockIdx.x * 32, n0 = blockIdx.y * 32;
    __shared__ float Ws[32][33];
    int tid = threadIdx.x;
    for (int l = 0; l < 4; l++) {
        int e = tid + 256 * l;
        int kk = e >> 5, nn = e & 31;
        Ws[kk][nn] = g[k0 + kk] * W[(size_t)(k0 + kk) * N + n0 + nn];
    }
    __syncthreads();
    for (int l = 0; l < 4; l++) {
        int e = tid + 256 * l;
        int nn = e >> 5, kk = e & 31;
        WT[(size_t)(n0 + nn) * K + k0 + kk] = f2b(Ws[kk][nn]);
    }
}

// ---------------- fused bias: out = b; out += lnb @ W (parallel over N x K-chunks) -------
__global__ __launch_bounds__(256) void bias_init(const float* __restrict__ b,
                                                 float* __restrict__ out, int N)
{
    int n = blockIdx.x * 256 + threadIdx.x;
    if (n < N) out[n] = b[n];
}

#define BKC 64
__global__ __launch_bounds__(256) void bias_reduce(const float* __restrict__ W,
                                                   const float* __restrict__ lnb,
                                                   float* __restrict__ out, int K, int N)
{
    int n = blockIdx.x * 256 + threadIdx.x;
    int k0 = blockIdx.y * BKC;
    if (n >= N) return;
    float s = 0.f;
    #pragma unroll 8
    for (int k = k0; k < k0 + BKC; k++) s += lnb[k] * W[(size_t)k * N + n];
    atomicAdd(&out[n], s);
}

// ---------------- staging helper: 128 rows x 32 cols bf16 tile via global_load_lds -------
__device__ __forceinline__ void stage_tile(const bf16* base, size_t ld, bf16* dst,
                                           int wave, int lane)
{
    int lrow = lane >> 2, lcol = lane & 3;
    for (int cc = 0; cc < 2; cc++) {
        int c = wave * 2 + cc;
        int row = c * 16 + lrow;
        const bf16* g = base + (size_t)row * ld + lcol * 8;
        __builtin_amdgcn_global_load_lds(AS1(g), AS3(dst + c * 512), 16, 0, 0);
    }
}

// ---------------- MFMA GEMM: C[m][n] = silu(A@B^T + bias) -------------------------------
__global__ __launch_bounds__(256) void gemm_mfma(
    const bf16* __restrict__ A, const bf16* __restrict__ BT,
    const float* __restrict__ bias, bf16* __restrict__ C,
    int M, int N, int K)
{
    __shared__ bf16 As[128 * BK];
    __shared__ bf16 Bs[128 * BK];
    int n0 = blockIdx.x * 128, m0 = blockIdx.y * 128;
    int tid = threadIdx.x, wave = tid >> 6, lane = tid & 63;
    int wm = wave & 1, wn = wave >> 1;
    float4v acc[4][4] = {};
    for (int k0 = 0; k0 < K; k0 += BK) {
        stage_tile(A  + (size_t)m0 * K + k0, K, As, wave, lane);
        stage_tile(BT + (size_t)n0 * K + k0, K, Bs, wave, lane);
        __syncthreads();
        int col = lane & 15, quad = lane >> 4;
        short8 a[4], b[4];
        for (int t = 0; t < 4; t++) {
            a[t] = *(const short8*)(As + (wm * 64 + t * 16 + col) * BK + quad * 8);
            b[t] = *(const short8*)(Bs + (wn * 64 + t * 16 + col) * BK + quad * 8);
        }
        for (int i = 0; i < 4; i++)
            for (int j = 0; j < 4; j++)
                acc[i][j] = MFMA(a[i], b[j], acc[i][j], 0, 0, 0);
        __syncthreads();
    }
    int col = lane & 15, quad = lane >> 4;
    for (int i = 0; i < 4; i++) {
        for (int j = 0; j < 4; j++) {
            int n = n0 + wn * 64 + j * 16 + col;
            float bs = bias[n];
            for (int r = 0; r < 4; r++) {
                int m = m0 + wm * 64 + i * 16 + quad * 4 + r;
                float v = acc[i][j][r] + bs;
                v = v / (1.f + __expf(-v));
                C[(size_t)m * N + n] = f2b(v);
            }
        }
    }
}

// ---------------- attn scores MFMA: P = relu(QK^T/256)^2, causal, bf16 ------------------
__global__ __launch_bounds__(256) void attn_score_mfma(
    const bf16* __restrict__ quadq, const bf16* __restrict__ quadk,
    bf16* __restrict__ P)
{
    int g = blockIdx.z, bi = blockIdx.y, bj = blockIdx.x;
    bf16* Pg = P + (size_t)g * GRP * GRP;
    int tid = threadIdx.x;
    if (bj > bi) {   // fully masked tile: write zeros
        short8 z = {};
        int rr = tid >> 1, half = tid & 1;
        short* dst = (short*)Pg + (size_t)(bi * 128 + rr) * GRP + bj * 128 + half * 64;
        for (int q = 0; q < 8; q++) ((short8*)dst)[q] = z;
        return;
    }
    __shared__ bf16 As[128 * BK];
    __shared__ bf16 Bs[128 * BK];
    int wave = tid >> 6, lane = tid & 63;
    int wm = wave & 1, wn = wave >> 1;
    float4v acc[4][4] = {};
    const bf16* Ab = quadq + (size_t)(g * GRP + bi * 128) * DQK;
    const bf16* Bb = quadk + (size_t)(g * GRP + bj * 128) * DQK;
    for (int k0 = 0; k0 < DQK; k0 += BK) {
        stage_tile(Ab + k0, DQK, As, wave, lane);
        stage_tile(Bb + k0, DQK, Bs, wave, lane);
        __syncthreads();
        int col = lane & 15, quad = lane >> 4;
        short8 a[4], b[4];
        for (int t = 0; t < 4; t++) {
            a[t] = *(const short8*)(As + (wm * 64 + t * 16 + col) * BK + quad * 8);
            b[t] = *(const short8*)(Bs + (wn * 64 + t * 16 + col) * BK + quad * 8);
        }
        for (int i = 0; i < 4; i++)
            for (int j = 0; j < 4; j++)
                acc[i][j] = MFMA(a[i], b[j], acc[i][j], 0, 0, 0);
        __syncthreads();
    }
    int col = lane & 15, quad = lane >> 4;
    for (int i = 0; i < 4; i++) {
        for (int j = 0; j < 4; j++) {
            int jj = bj * 128 + wn * 64 + j * 16 + col;
            for (int r = 0; r < 4; r++) {
                int ii = bi * 128 + wm * 64 + i * 16 + quad * 4 + r;
                float s = acc[i][j][r] * (1.f / GRP);
                s = fmaxf(s, 0.f); s = s * s;
                if (jj > ii) s = 0.f;
                Pg[(size_t)ii * GRP + jj] = f2b(s);
            }
        }
    }
}

// ---------------- linkv MFMA: linkvT[g][e][d] = (hidT_g @ linkT_g^T)/256 ----------------
__global__ __launch_bounds__(256) void linkv_mfma(
    const bf16* __restrict__ hidT, const bf16* __restrict__ linkT,
    float* __restrict__ linkvT, int rowsC)
{
    int g = blockIdx.z, eb = blockIdx.y;
    int e0 = eb * 128;
    __shared__ bf16 As[128 * BK];
    __shared__ bf16 Bs[128 * BK];
    int tid = threadIdx.x, wave = tid >> 6, lane = tid & 63;
    int wm = wave & 1, wn = wave >> 1;
    float4v acc[4][4] = {};
    for (int k0 = 0; k0 < GRP; k0 += BK) {
        stage_tile(hidT  + (size_t)e0 * rowsC + g * GRP + k0, rowsC, As, wave, lane);
        stage_tile(linkT + (size_t)0  * rowsC + g * GRP + k0, rowsC, Bs, wave, lane);
        __syncthreads();
        int col = lane & 15, quad = lane >> 4;
        short8 a[4], b[4];
        for (int t = 0; t < 4; t++) {
            a[t] = *(const short8*)(As + (wm * 64 + t * 16 + col) * BK + quad * 8);
            b[t] = *(const short8*)(Bs + (wn * 64 + t * 16 + col) * BK + quad * 8);
        }
        for (int i = 0; i < 4; i++)
            for (int j = 0; j < 4; j++)
                acc[i][j] = MFMA(a[i], b[j], acc[i][j], 0, 0, 0);
        __syncthreads();
    }
    float* out = linkvT + (size_t)g * (HID * DQK);
    int col = lane & 15, quad = lane >> 4;
    for (int i = 0; i < 4; i++) {
        for (int j = 0; j < 4; j++) {
            int d = wn * 64 + j * 16 + col;
            for (int r = 0; r < 4; r++) {
                int e = e0 + wm * 64 + i * 16 + quad * 4 + r;
                out[(size_t)e * DQK + d] = acc[i][j][r] * (1.f / GRP);
            }
        }
    }
}

// ---------------- exclusive cumsum over group axis ---------------------------------------
__global__ void cumsum_kernel(float* __restrict__ linkv)
{
    long idx = (long)blockIdx.x * blockDim.x + threadIdx.x;
    int b = (int)(idx / (DQK * HID));
    long off = idx % (DQK * HID);
    float* p = linkv + (long)b * NG * DQK * HID + off;
    float run = 0.f;
    for (int gi = 0; gi < NG; gi++) {
        float v = p[(long)gi * DQK * HID];
        p[(long)gi * DQK * HID] = run;
        run += v;
    }
}

// ---------------- fused attn apply MFMA + gating -----------------------------------------
__global__ __launch_bounds__(256) void attn_apply_mfma(
    const bf16* __restrict__ P, const bf16* __restrict__ hidT,
    const bf16* __restrict__ linq, const float* __restrict__ linkvT,
    const bf16* __restrict__ hid, bf16* __restrict__ outg, int rowsC)
{
    int g = blockIdx.z, mb = blockIdx.y, e0 = blockIdx.x * 64;
    __shared__ bf16 As[128 * BK];
    __shared__ bf16 Bs[128 * BK];
    int tid = threadIdx.x, wave = tid >> 6, lane = tid & 63;
    int lrow = lane >> 2, lcol = lane & 3;
    int m0 = mb * 128;
    float4v acc[2][8] = {};
    const bf16* Pg = P + (size_t)g * GRP * GRP;
    // phase 1: quadratic, K = 256 over j
    for (int j0 = 0; j0 < GRP; j0 += BK) {
        for (int cc = 0; cc < 2; cc++) {
            int c = wave * 2 + cc;
            int row = c * 16 + lrow;
            const bf16* ga = Pg + (size_t)(m0 + row) * GRP + j0 + lcol * 8;
            __builtin_amdgcn_global_load_lds(AS1(ga), AS3(As + c * 512), 16, 0, 0);
            int er = (c < 4) ? (e0 + row) : (1024 + e0 + (row - 64));
            const bf16* gb = hidT + (size_t)er * rowsC + g * GRP + j0 + lcol * 8;
            __builtin_amdgcn_global_load_lds(AS1(gb), AS3(Bs + c * 512), 16, 0, 0);
        }
        __syncthreads();
        int col = lane & 15, quad = lane >> 4;
        short8 a[2], b[8];
        for (int t = 0; t < 2; t++)
            a[t] = *(const short8*)(As + (wave * 32 + t * 16 + col) * BK + quad * 8);
        for (int t = 0; t < 8; t++)
            b[t] = *(const short8*)(Bs + (t * 16 + col) * BK + quad * 8);
        for (int i = 0; i < 2; i++)
            for (int j = 0; j < 8; j++)
                acc[i][j] = MFMA(a[i], b[j], acc[i][j], 0, 0, 0);
        __syncthreads();
    }
    // phase 2: linear, K = 128 over d
    const float* Lg = linkvT + (size_t)g * (HID * DQK);
    for (int d0 = 0; d0 < DQK; d0 += BK) {
        for (int cc = 0; cc < 2; cc++) {
            int c = wave * 2 + cc;
            int row = c * 16 + lrow;
            const bf16* ga = linq + (size_t)(g * GRP + m0 + row) * DQK + d0 + lcol * 8;
            __builtin_amdgcn_global_load_lds(AS1(ga), AS3(As + c * 512), 16, 0, 0);
        }
        {   // manual B staging: fp32 linkvT -> bf16 LDS
            int rr = tid >> 1, half = tid & 1;
            int er = (rr < 64) ? (e0 + rr) : (1024 + e0 + (rr - 64));
            const float* src = Lg + (size_t)er * DQK + d0 + half * 16;
            bf16* dstp = Bs + rr * BK + half * 16;
            for (int q = 0; q < 4; q++) {
                float4v f = *(const float4v*)(src + q * 4);
                dstp[q * 4 + 0] = f2b(f[0]); dstp[q * 4 + 1] = f2b(f[1]);
                dstp[q * 4 + 2] = f2b(f[2]); dstp[q * 4 + 3] = f2b(f[3]);
            }
        }
        __syncthreads();
        int col = lane & 15, quad = lane >> 4;
        short8 a[2], b[8];
        for (int t = 0; t < 2; t++)
            a[t] = *(const short8*)(As + (wave * 32 + t * 16 + col) * BK + quad * 8);
        for (int t = 0; t < 8; t++)
            b[t] = *(const short8*)(Bs + (t * 16 + col) * BK + quad * 8);
        for (int i = 0; i < 2; i++)
            for (int j = 0; j < 8; j++)
                acc[i][j] = MFMA(a[i], b[j], acc[i][j], 0, 0, 0);
        __syncthreads();
    }
    // epilogue with gating
    int col = lane & 15, quad = lane >> 4;
    for (int mt = 0; mt < 2; mt++) {
        for (int nt = 0; nt < 4; nt++) {
            for (int r = 0; r < 4; r++) {
                int tokg = g * GRP + m0 + wave * 32 + mt * 16 + quad * 4 + r;
                int e = e0 + nt * 16 + col;
                float av = acc[mt][nt][r];
                float au = acc[mt][nt + 4][r];
                float v = b2f(hid[(size_t)tokg * HID + e]);
                float u = b2f(hid[(size_t)tokg * HID + 1024 + e]);
                float gate = 1.f / (1.f + __expf(-av * u));
                outg[(size_t)tokg * 1024 + e] = f2b(au * v * gate);
            }
        }
    }
}

// ---------------- qk affine split: quadq/quadk/linq natural + linkT transposed -----------
__global__ __launch_bounds__(256) void qk_affine(
    const bf16* __restrict__ qkb, const float* __restrict__ gamma,
    const float* __restrict__ beta,
    bf16* __restrict__ quadq, bf16* __restrict__ quadk,
    bf16* __restrict__ linq, bf16* __restrict__ linkT, int rowsC)
{
    int t0 = blockIdx.x * 64;
    __shared__ bf16 L[64][DQK + 2];
    int tid = threadIdx.x;
    int d = tid & 127, tl = tid >> 7;
    for (int l = 0; l < 32; l++) {
        int tok = t0 + tl + 2 * l;
        float q = b2f(qkb[(size_t)tok * DQK + d]);
        quadq[(size_t)tok * DQK + d] = f2b(q * gamma[0 * DQK + d] + beta[0 * DQK + d]);
        linq [(size_t)tok * DQK + d] = f2b(q * gamma[1 * DQK + d] + beta[1 * DQK + d]);
        quadk[(size_t)tok * DQK + d] = f2b(q * gamma[2 * DQK + d] + beta[2 * DQK + d]);
        L[tok - t0][d] = f2b(q * gamma[3 * DQK + d] + beta[3 * DQK + d]);
    }
    __syncthreads();
    int dd = tid >> 1, half = tid & 1;
    for (int t = 0; t < 32; t++) {
        int tok = half * 32 + t;
        linkT[(size_t)dd * rowsC + t0 + tok] = L[tok][dd];
    }
}

// ---------------- dwconv (generic) + final fp32 variant ----------------------------------
template<typename TO>
__global__ __launch_bounds__(256) void dwconv_res(
    const bf16* __restrict__ src, const float* __restrict__ dw,
    const float* __restrict__ xres, TO* __restrict__ dst, int C)
{
    int c0 = blockIdx.x * 64;
    int t0 = blockIdx.y * 64;
    int b  = blockIdx.z;
    __shared__ float s[80][64];
    int tid = threadIdx.x;
    int c = tid & 63;
    int rp = tid >> 6;
    const bf16* base = src + (size_t)b * NN * C;
    for (int l = 0; l < 20; l++) {
        int tt = rp + l * 4;
        int t = t0 + tt - 8;
        float v = 0.f;
        if (t >= 0 && t < NN) v = b2f(base[(size_t)t * C + c0 + c]);
        s[tt][c] = v;
    }
    __syncthreads();
    float w[KW];
    for (int k = 0; k < KW; k++) w[k] = dw[k * C + c0 + c];
    for (int l = 0; l < 16; l++) {
        int r = rp + l * 4;
        float acc = s[r + 8][c];
        for (int k = 0; k < KW; k++) acc += s[r + k][c] * w[k];
        long gidx = ((long)b * NN + t0 + r) * C + c0 + c;
        if (xres) acc += xres[gidx];
        stv(dst, gidx, acc);
    }
}

// dwconv for h: writes hid [tok][2048] AND hidT [2048][rowsC]
__global__ __launch_bounds__(256) void dwconv_dual(
    const bf16* __restrict__ src, const float* __restrict__ dw,
    bf16* __restrict__ dst, bf16* __restrict__ dstT, int rowsC)
{
    int c0 = blockIdx.x * 64, t0 = blockIdx.y * 64, b = blockIdx.z;
    __shared__ float s[80][64];
    __shared__ bf16 o[64][65];
    int tid = threadIdx.x;
    int c = tid & 63, rp = tid >> 6;
    const bf16* base = src + (size_t)b * NN * HID + c0;
    for (int l = 0; l < 20; l++) {
        int tt = rp + l * 4;
        int t = t0 + tt - 8;
        float v = 0.f;
        if (t >= 0 && t < NN) v = b2f(base[(size_t)t * HID + c]);
        s[tt][c] = v;
    }
    __syncthreads();
    float w[KW];
    for (int k = 0; k < KW; k++) w[k] = dw[k * HID + c0 + c];
    for (int l = 0; l < 16; l++) {
        int r = rp + l * 4;
        float acc = s[r + 8][c];
        for (int k = 0; k < KW; k++) acc += s[r + k][c] * w[k];
        bf16 hv = f2b(acc);
        dst[((size_t)b * NN + t0 + r) * HID + c0 + c] = hv;
        o[c][r] = hv;
    }
    __syncthreads();
    int ch = tid >> 2, seg = tid & 3;
    for (int t = 0; t < 16; t++) {
        int tok = seg * 16 + t;
        dstT[(size_t)(c0 + ch) * rowsC + b * NN + t0 + tok] = o[ch][tok];
    }
}

extern "C" void kernel_launch(void* const* d_in, const int* in_sizes, int n_in,
                              void* d_out, int out_size, void* d_ws, size_t ws_size,
                              hipStream_t stream)
{
    const float* x      = (const float*)d_in[0];
    const float* ln_h_g = (const float*)d_in[1];
    const float* ln_h_b = (const float*)d_in[2];
    const float* W_h    = (const float*)d_in[3];
    const float* b_h    = (const float*)d_in[4];
    const float* dw_h   = (const float*)d_in[5];
    const float* ln_qk_g= (const float*)d_in[6];
    const float* ln_qk_b= (const float*)d_in[7];
    const float* W_qk   = (const float*)d_in[8];
    const float* b_qk   = (const float*)d_in[9];
    const float* dw_qk  = (const float*)d_in[10];
    const float* gamma  = (const float*)d_in[11];
    const float* beta   = (const float*)d_in[12];
    const float* ln_o_g = (const float*)d_in[13];
    const float* ln_o_b = (const float*)d_in[14];
    const float* W_o    = (const float*)d_in[15];
    const float* b_o    = (const float*)d_in[16];
    const float* dw_o   = (const float*)d_in[17];
    float* outp = (float*)d_out;

    // ---- fixed region: transposed/scaled weights + fused biases ----
    char* p = (char*)d_ws;
    bf16* WT_h  = (bf16*)p;  p += (size_t)HID * DIM * 2;
    bf16* WT_qk = (bf16*)p;  p += (size_t)DQK * DIM * 2;
    bf16* WT_o  = (bf16*)p;  p += (size_t)DIM * 1024 * 2;
    float* bias_h  = (float*)p; p += HID * 4;
    float* bias_qk = (float*)p; p += DQK * 4;
    float* bias_o  = (float*)p; p += DIM * 4;
    p = (char*)(((uintptr_t)p + 255) & ~(uintptr_t)255);
    size_t fixed = (size_t)(p - (char*)d_ws);

    auto bytes_for = [fixed](int cb) -> size_t {
        size_t rows = (size_t)cb * NN;
        size_t s_big = rows * HID * 2;
        size_t s_out = rows * 1024 * 2;
        size_t s_hat = rows * DIM * 2;
        size_t s_qk  = rows * DQK * 2;
        return fixed + 3 * s_big + s_out + s_hat + 5 * s_qk + 4096;
    };
    int CB = 1;
    if (bytes_for(4) <= ws_size) CB = 4;
    else if (bytes_for(2) <= ws_size) CB = 2;
    const int rowsC = CB * NN;
    const size_t rows = (size_t)rowsC;

    char* s1 = p;               p += rows * HID * 2;   // h -> linkvT -> fin_pre
    char* s2 = p;               p += rows * HID * 2;   // hid -> hat2
    char* s3 = p;               p += rows * HID * 2;   // hidT
    char* s4 = p;               p += rows * 1024 * 2;  // outg
    char* s5 = p;               p += rows * DIM * 2;   // hat1 -> P
    char* s6 = p;               p += rows * DQK * 2;   // qk_pre -> linkT
    char* s7 = p;               p += rows * DQK * 2;   // qkb
    char* s8 = p;               p += rows * DQK * 2;   // quadq
    char* s9 = p;               p += rows * DQK * 2;   // quadk
    char* s10 = p;              p += rows * DQK * 2;   // linq

    bf16*  h       = (bf16*)s1;
    float* linkvT  = (float*)s1;
    bf16*  fin_pre = (bf16*)s1;
    bf16*  hid     = (bf16*)s2;
    bf16*  hat2    = (bf16*)s2;
    bf16*  hidT    = (bf16*)s3;
    bf16*  outg    = (bf16*)s4;
    bf16*  hat1    = (bf16*)s5;
    bf16*  P       = (bf16*)s5;
    bf16*  qk_pre  = (bf16*)s6;
    bf16*  linkT   = (bf16*)s6;
    bf16*  qkb     = (bf16*)s7;
    bf16*  quadq   = (bf16*)s8;
    bf16*  quadk   = (bf16*)s9;
    bf16*  linq    = (bf16*)s10;

    // ---- weight prep (fold LN affine into weights/biases) ----
    prep_wT<<<dim3(DIM / 32, HID / 32), 256, 0, stream>>>(W_h, ln_h_g, WT_h, DIM, HID);
    prep_wT<<<dim3(DIM / 32, DQK / 32), 256, 0, stream>>>(W_qk, ln_qk_g, WT_qk, DIM, DQK);
    prep_wT<<<dim3(1024 / 32, DIM / 32), 256, 0, stream>>>(W_o, ln_o_g, WT_o, 1024, DIM);
    bias_init<<<HID / 256, 256, 0, stream>>>(b_h, bias_h, HID);
    bias_init<<<1, 256, 0, stream>>>(b_qk, bias_qk, DQK);
    bias_init<<<2, 256, 0, stream>>>(b_o, bias_o, DIM);
    bias_reduce<<<dim3(HID / 256, DIM / BKC), 256, 0, stream>>>(W_h, ln_h_b, bias_h, DIM, HID);
    bias_reduce<<<dim3(1, DIM / BKC), 256, 0, stream>>>(W_qk, ln_qk_b, bias_qk, DIM, DQK);
    bias_reduce<<<dim3(2, 1024 / BKC), 256, 0, stream>>>(W_o, ln_o_b, bias_o, 1024, DIM);

    const int G = CB * NG;   // groups per chunk
    for (int b0 = 0; b0 < BB; b0 += CB) {
        const float* xc = x    + (size_t)b0 * NN * DIM;
        float* outc     = outp + (size_t)b0 * NN * DIM;
        int R = rowsC;

        // 1) LN of token-shifted x -> hat1
        ln_kernel<float, DIM, 1><<<R, 256, 0, stream>>>(xc, hat1);
        // 2) h = silu(hat1 @ W_h' + bias_h')
        gemm_mfma<<<dim3(HID / 128, R / 128), 256, 0, stream>>>(hat1, WT_h, bias_h, h, R, HID, DIM);
        // 3) qk_pre = silu(hat1 @ W_qk' + bias_qk')
        gemm_mfma<<<dim3(1, R / 128), 256, 0, stream>>>(hat1, WT_qk, bias_qk, qk_pre, R, DQK, DIM);
        // 4) hid + hidT = h + dwconv(h)
        dwconv_dual<<<dim3(HID / 64, NN / 64, CB), 256, 0, stream>>>(h, dw_h, hid, hidT, rowsC);
        // 5) qkb = qk_pre + dwconv(qk_pre)
        dwconv_res<bf16><<<dim3(DQK / 64, NN / 64, CB), 256, 0, stream>>>(qk_pre, dw_qk, nullptr, qkb, DQK);
        // 6) qk affine -> quadq/quadk/linq (natural) + linkT (transposed)
        qk_affine<<<R / 64, 256, 0, stream>>>(qkb, gamma, beta, quadq, quadk, linq, linkT, rowsC);
        // 7) quadratic scores -> P (bf16)
        attn_score_mfma<<<dim3(2, 2, G), 256, 0, stream>>>(quadq, quadk, P);
        // 8) linear attention kv -> linkvT [g][e][d] fp32
        linkv_mfma<<<dim3(1, HID / 128, G), 256, 0, stream>>>(hidT, linkT, linkvT, rowsC);
        // 9) exclusive cumsum over groups (in-place)
        cumsum_kernel<<<(CB * DQK * HID) / 256, 256, 0, stream>>>(linkvT);
        // 10) fused apply + gating -> outg
        attn_apply_mfma<<<dim3(16, 2, G), 256, 0, stream>>>(P, hidT, linq, linkvT, hid, outg, rowsC);
        // 11) LN(outg) -> hat2
        ln_kernel_bf<1024><<<R, 256, 0, stream>>>(outg, hat2);
        // 12) fin_pre = silu(hat2 @ W_o' + bias_o')
        gemm_mfma<<<dim3(DIM / 128, R / 128), 256, 0, stream>>>(hat2, WT_o, bias_o, fin_pre, R, DIM, 1024);
        // 13) d_out(fp32) = x + fin_pre + dwconv(fin_pre)
        dwconv_res<float><<<dim3(DIM / 64, NN / 64, CB), 256, 0, stream>>>(fin_pre, dw_o, xc, outc, DIM);
    }
}

// Round 9
// 602.346 us; speedup vs baseline: 4.6668x; 1.0170x over previous
//
#include <hip/hip_runtime.h>
#include <hip/hip_bf16.h>

typedef __hip_bfloat16 bf16;
typedef __attribute__((ext_vector_type(8))) short short8;
typedef __attribute__((ext_vector_type(4))) float float4v;
__device__ __forceinline__ float b2f(bf16 v){ return __bfloat162float(v); }
__device__ __forceinline__ bf16 f2b(float v){ return __float2bfloat16(v); }
__device__ __forceinline__ void stv(float* p, long i, float v){ p[i] = v; }
__device__ __forceinline__ void stv(bf16*  p, long i, float v){ p[i] = f2b(v); }

#define MFMA __builtin_amdgcn_mfma_f32_16x16x32_bf16
#define AS1(p) ((const __attribute__((address_space(1))) void*)(p))
#define AS3(p) ((__attribute__((address_space(3))) void*)(p))

// Problem constants
#define BB   8
#define NN   2048
#define DIM  512
#define HID  2048
#define DQK  128
#define GRP  256
#define NG   8
#define KW   17
#define BK   32
#define NHQ  2176   // merged N for h(2048) + qk(128) gemm; 17 * 128

// ---------------- LayerNorm (token-shift variant for x, plain bf16 variant) ------------
template<typename TI, int D, int SHIFT_HALF>
__global__ __launch_bounds__(256) void ln_kernel(const TI* __restrict__ in,
                                                 bf16* __restrict__ out)
{
    int row = blockIdx.x;
    int t = row % NN;
    int tid = threadIdx.x;
    const int PT = D / 256;
    float vals[PT];
    float s = 0.f, ss = 0.f;
    for (int i = 0; i < PT; i++) {
        int c = tid + i * 256;
        float v;
        if (SHIFT_HALF && c < D / 2) {
            v = (t > 0) ? (float)(in[((long)row - 1) * D + c]) : 0.f;
        } else {
            v = (float)(in[(long)row * D + c]);
        }
        vals[i] = v; s += v; ss += v * v;
    }
    for (int o = 32; o > 0; o >>= 1) { s += __shfl_down(s, o); ss += __shfl_down(ss, o); }
    __shared__ float sm[4], sm2[4];
    int wid = tid >> 6, lane = tid & 63;
    if (lane == 0) { sm[wid] = s; sm2[wid] = ss; }
    __syncthreads();
    if (tid == 0) {
        float a = 0.f, q = 0.f;
        for (int w = 0; w < 4; w++) { a += sm[w]; q += sm2[w]; }
        sm[0] = a; sm2[0] = q;
    }
    __syncthreads();
    float mean = sm[0] / D;
    float var  = fmaxf(sm2[0] / D - mean * mean, 0.f);
    float rs = rsqrtf(var + 1e-5f);
    for (int i = 0; i < PT; i++) {
        int c = tid + i * 256;
        out[(long)row * D + c] = f2b((vals[i] - mean) * rs);
    }
}

template<int D>
__global__ __launch_bounds__(256) void ln_kernel_bf(const bf16* __restrict__ in,
                                                    bf16* __restrict__ out)
{
    int row = blockIdx.x;
    int tid = threadIdx.x;
    const int PT = D / 256;
    float vals[PT];
    float s = 0.f, ss = 0.f;
    for (int i = 0; i < PT; i++) {
        int c = tid + i * 256;
        float v = b2f(in[(long)row * D + c]);
        vals[i] = v; s += v; ss += v * v;
    }
    for (int o = 32; o > 0; o >>= 1) { s += __shfl_down(s, o); ss += __shfl_down(ss, o); }
    __shared__ float sm[4], sm2[4];
    int wid = tid >> 6, lane = tid & 63;
    if (lane == 0) { sm[wid] = s; sm2[wid] = ss; }
    __syncthreads();
    if (tid == 0) {
        float a = 0.f, q = 0.f;
        for (int w = 0; w < 4; w++) { a += sm[w]; q += sm2[w]; }
        sm[0] = a; sm2[0] = q;
    }
    __syncthreads();
    float mean = sm[0] / D;
    float var  = fmaxf(sm2[0] / D - mean * mean, 0.f);
    float rs = rsqrtf(var + 1e-5f);
    for (int i = 0; i < PT; i++) {
        int c = tid + i * 256;
        out[(long)row * D + c] = f2b((vals[i] - mean) * rs);
    }
}

// ---------------- weight prep: WT[n][k] = bf16(g[k]*W[k][n]) -----------------------------
__global__ __launch_bounds__(256) void prep_wT(const float* __restrict__ W,
                                               const float* __restrict__ g,
                                               bf16* __restrict__ WT, int K, int N)
{
    int k0 = blockIdx.x * 32, n0 = blockIdx.y * 32;
    __shared__ float Ws[32][33];
    int tid = threadIdx.x;
    for (int l = 0; l < 4; l++) {
        int e = tid + 256 * l;
        int kk = e >> 5, nn = e & 31;
        Ws[kk][nn] = g[k0 + kk] * W[(size_t)(k0 + kk) * N + n0 + nn];
    }
    __syncthreads();
    for (int l = 0; l < 4; l++) {
        int e = tid + 256 * l;
        int nn = e >> 5, kk = e & 31;
        WT[(size_t)(n0 + nn) * K + k0 + kk] = f2b(Ws[kk][nn]);
    }
}

// ---------------- fused bias: out = b; out += lnb @ W ------------------------------------
__global__ __launch_bounds__(256) void bias_init(const float* __restrict__ b,
                                                 float* __restrict__ out, int N)
{
    int n = blockIdx.x * 256 + threadIdx.x;
    if (n < N) out[n] = b[n];
}

#define BKC 64
__global__ __launch_bounds__(256) void bias_reduce(const float* __restrict__ W,
                                                   const float* __restrict__ lnb,
                                                   float* __restrict__ out, int K, int N)
{
    int n = blockIdx.x * 256 + threadIdx.x;
    int k0 = blockIdx.y * BKC;
    if (n >= N) return;
    float s = 0.f;
    #pragma unroll 8
    for (int k = k0; k < k0 + BKC; k++) s += lnb[k] * W[(size_t)k * N + n];
    atomicAdd(&out[n], s);
}

// ---------------- staging helper: 128 rows x 32 cols bf16 tile via global_load_lds -------
__device__ __forceinline__ void stage_tile(const bf16* base, size_t ld, bf16* dst,
                                           int wave, int lane)
{
    int lrow = lane >> 2, lcol = lane & 3;
    for (int cc = 0; cc < 2; cc++) {
        int c = wave * 2 + cc;
        int row = c * 16 + lrow;
        const bf16* g = base + (size_t)row * ld + lcol * 8;
        __builtin_amdgcn_global_load_lds(AS1(g), AS3(dst + c * 512), 16, 0, 0);
    }
}

// ---------------- MFMA GEMM: C[m][n] = silu(A@B^T + bias), ldC output stride -------------
__global__ __launch_bounds__(256) void gemm_mfma(
    const bf16* __restrict__ A, const bf16* __restrict__ BT,
    const float* __restrict__ bias, bf16* __restrict__ C,
    int M, int N, int K, int ldC)
{
    __shared__ bf16 As[128 * BK];
    __shared__ bf16 Bs[128 * BK];
    int n0 = blockIdx.x * 128, m0 = blockIdx.y * 128;
    int tid = threadIdx.x, wave = tid >> 6, lane = tid & 63;
    int wm = wave & 1, wn = wave >> 1;
    float4v acc[4][4] = {};
    for (int k0 = 0; k0 < K; k0 += BK) {
        stage_tile(A  + (size_t)m0 * K + k0, K, As, wave, lane);
        stage_tile(BT + (size_t)n0 * K + k0, K, Bs, wave, lane);
        __syncthreads();
        int col = lane & 15, quad = lane >> 4;
        short8 a[4], b[4];
        for (int t = 0; t < 4; t++) {
            a[t] = *(const short8*)(As + (wm * 64 + t * 16 + col) * BK + quad * 8);
            b[t] = *(const short8*)(Bs + (wn * 64 + t * 16 + col) * BK + quad * 8);
        }
        for (int i = 0; i < 4; i++)
            for (int j = 0; j < 4; j++)
                acc[i][j] = MFMA(a[i], b[j], acc[i][j], 0, 0, 0);
        __syncthreads();
    }
    int col = lane & 15, quad = lane >> 4;
    for (int i = 0; i < 4; i++) {
        for (int j = 0; j < 4; j++) {
            int n = n0 + wn * 64 + j * 16 + col;
            float bs = bias[n];
            for (int r = 0; r < 4; r++) {
                int m = m0 + wm * 64 + i * 16 + quad * 4 + r;
                float v = acc[i][j][r] + bs;
                v = v / (1.f + __expf(-v));
                C[(size_t)m * ldC + n] = f2b(v);
            }
        }
    }
}

// ---------------- attn scores MFMA: P = relu(QK^T/256)^2, causal, bf16 ------------------
__global__ __launch_bounds__(256) void attn_score_mfma(
    const bf16* __restrict__ quadq, const bf16* __restrict__ quadk,
    bf16* __restrict__ P)
{
    int g = blockIdx.z, bi = blockIdx.y, bj = blockIdx.x;
    bf16* Pg = P + (size_t)g * GRP * GRP;
    int tid = threadIdx.x;
    if (bj > bi) {   // fully masked tile: write zeros
        short8 z = {};
        int rr = tid >> 1, half = tid & 1;
        short* dst = (short*)Pg + (size_t)(bi * 128 + rr) * GRP + bj * 128 + half * 64;
        for (int q = 0; q < 8; q++) ((short8*)dst)[q] = z;
        return;
    }
    __shared__ bf16 As[128 * BK];
    __shared__ bf16 Bs[128 * BK];
    int wave = tid >> 6, lane = tid & 63;
    int wm = wave & 1, wn = wave >> 1;
    float4v acc[4][4] = {};
    const bf16* Ab = quadq + (size_t)(g * GRP + bi * 128) * DQK;
    const bf16* Bb = quadk + (size_t)(g * GRP + bj * 128) * DQK;
    for (int k0 = 0; k0 < DQK; k0 += BK) {
        stage_tile(Ab + k0, DQK, As, wave, lane);
        stage_tile(Bb + k0, DQK, Bs, wave, lane);
        __syncthreads();
        int col = lane & 15, quad = lane >> 4;
        short8 a[4], b[4];
        for (int t = 0; t < 4; t++) {
            a[t] = *(const short8*)(As + (wm * 64 + t * 16 + col) * BK + quad * 8);
            b[t] = *(const short8*)(Bs + (wn * 64 + t * 16 + col) * BK + quad * 8);
        }
        for (int i = 0; i < 4; i++)
            for (int j = 0; j < 4; j++)
                acc[i][j] = MFMA(a[i], b[j], acc[i][j], 0, 0, 0);
        __syncthreads();
    }
    int col = lane & 15, quad = lane >> 4;
    for (int i = 0; i < 4; i++) {
        for (int j = 0; j < 4; j++) {
            int jj = bj * 128 + wn * 64 + j * 16 + col;
            for (int r = 0; r < 4; r++) {
                int ii = bi * 128 + wm * 64 + i * 16 + quad * 4 + r;
                float s = acc[i][j][r] * (1.f / GRP);
                s = fmaxf(s, 0.f); s = s * s;
                if (jj > ii) s = 0.f;
                Pg[(size_t)ii * GRP + jj] = f2b(s);
            }
        }
    }
}

// ---------------- linkv MFMA: linkvT[g][e][d] = (hidT_g @ linkT_g^T)/256 ----------------
__global__ __launch_bounds__(256) void linkv_mfma(
    const bf16* __restrict__ hidT, const bf16* __restrict__ linkT,
    float* __restrict__ linkvT, int rowsC)
{
    int g = blockIdx.z, eb = blockIdx.y;
    int e0 = eb * 128;
    __shared__ bf16 As[128 * BK];
    __shared__ bf16 Bs[128 * BK];
    int tid = threadIdx.x, wave = tid >> 6, lane = tid & 63;
    int wm = wave & 1, wn = wave >> 1;
    float4v acc[4][4] = {};
    for (int k0 = 0; k0 < GRP; k0 += BK) {
        stage_tile(hidT  + (size_t)e0 * rowsC + g * GRP + k0, rowsC, As, wave, lane);
        stage_tile(linkT + (size_t)0  * rowsC + g * GRP + k0, rowsC, Bs, wave, lane);
        __syncthreads();
        int col = lane & 15, quad = lane >> 4;
        short8 a[4], b[4];
        for (int t = 0; t < 4; t++) {
            a[t] = *(const short8*)(As + (wm * 64 + t * 16 + col) * BK + quad * 8);
            b[t] = *(const short8*)(Bs + (wn * 64 + t * 16 + col) * BK + quad * 8);
        }
        for (int i = 0; i < 4; i++)
            for (int j = 0; j < 4; j++)
                acc[i][j] = MFMA(a[i], b[j], acc[i][j], 0, 0, 0);
        __syncthreads();
    }
    float* out = linkvT + (size_t)g * (HID * DQK);
    int col = lane & 15, quad = lane >> 4;
    for (int i = 0; i < 4; i++) {
        for (int j = 0; j < 4; j++) {
            int d = wn * 64 + j * 16 + col;
            for (int r = 0; r < 4; r++) {
                int e = e0 + wm * 64 + i * 16 + quad * 4 + r;
                out[(size_t)e * DQK + d] = acc[i][j][r] * (1.f / GRP);
            }
        }
    }
}

// ---------------- exclusive cumsum over group axis, fp32 in -> bf16 out -----------------
__global__ void cumsum_bf(const float* __restrict__ in, bf16* __restrict__ out)
{
    long idx = (long)blockIdx.x * blockDim.x + threadIdx.x;
    int b = (int)(idx / (DQK * HID));
    long off = idx % (DQK * HID);
    const float* pi = in + (long)b * NG * DQK * HID + off;
    bf16* po = out + (long)b * NG * DQK * HID + off;
    float run = 0.f;
    for (int gi = 0; gi < NG; gi++) {
        po[(long)gi * DQK * HID] = f2b(run);
        run += pi[(long)gi * DQK * HID];
    }
}

// ---------------- fused attn apply MFMA + gating (256-token blocks) ----------------------
// Block: full group (256 tokens) x 64 e-pairs. Wave = 64 tokens. acc[4][8].
__global__ __launch_bounds__(256) void attn_apply_mfma(
    const bf16* __restrict__ P, const bf16* __restrict__ hidT,
    const bf16* __restrict__ linq, const bf16* __restrict__ linkvb,
    const bf16* __restrict__ hid, bf16* __restrict__ outg, int rowsC)
{
    int g = blockIdx.y, e0 = blockIdx.x * 64;
    __shared__ bf16 As[256 * BK];
    __shared__ bf16 Bs[128 * BK];
    int tid = threadIdx.x, wave = tid >> 6, lane = tid & 63;
    int lrow = lane >> 2, lcol = lane & 3;
    float4v acc[4][8] = {};
    const bf16* Pg = P + (size_t)g * GRP * GRP;
    // phase 1: quadratic, K = 256 over j
    for (int j0 = 0; j0 < GRP; j0 += BK) {
        for (int cc = 0; cc < 4; cc++) {
            int c = wave * 4 + cc;               // 0..15
            int row = c * 16 + lrow;             // 0..255
            const bf16* ga = Pg + (size_t)row * GRP + j0 + lcol * 8;
            __builtin_amdgcn_global_load_lds(AS1(ga), AS3(As + c * 512), 16, 0, 0);
        }
        for (int cc = 0; cc < 2; cc++) {
            int c = wave * 2 + cc;               // 0..7
            int row = c * 16 + lrow;             // 0..127
            int er = (row < 64) ? (e0 + row) : (1024 + e0 + (row - 64));
            const bf16* gb = hidT + (size_t)er * rowsC + g * GRP + j0 + lcol * 8;
            __builtin_amdgcn_global_load_lds(AS1(gb), AS3(Bs + c * 512), 16, 0, 0);
        }
        __syncthreads();
        int col = lane & 15, quad = lane >> 4;
        short8 a[4], b[8];
        for (int t = 0; t < 4; t++)
            a[t] = *(const short8*)(As + (wave * 64 + t * 16 + col) * BK + quad * 8);
        for (int t = 0; t < 8; t++)
            b[t] = *(const short8*)(Bs + (t * 16 + col) * BK + quad * 8);
        for (int i = 0; i < 4; i++)
            for (int j = 0; j < 8; j++)
                acc[i][j] = MFMA(a[i], b[j], acc[i][j], 0, 0, 0);
        __syncthreads();
    }
    // phase 2: linear, K = 128 over d (linkvb already bf16 exclusive prefix)
    const bf16* Lg = linkvb + (size_t)g * (HID * DQK);
    for (int d0 = 0; d0 < DQK; d0 += BK) {
        for (int cc = 0; cc < 4; cc++) {
            int c = wave * 4 + cc;
            int row = c * 16 + lrow;
            const bf16* ga = linq + (size_t)(g * GRP + row) * DQK + d0 + lcol * 8;
            __builtin_amdgcn_global_load_lds(AS1(ga), AS3(As + c * 512), 16, 0, 0);
        }
        for (int cc = 0; cc < 2; cc++) {
            int c = wave * 2 + cc;
            int row = c * 16 + lrow;
            int er = (row < 64) ? (e0 + row) : (1024 + e0 + (row - 64));
            const bf16* gb = Lg + (size_t)er * DQK + d0 + lcol * 8;
            __builtin_amdgcn_global_load_lds(AS1(gb), AS3(Bs + c * 512), 16, 0, 0);
        }
        __syncthreads();
        int col = lane & 15, quad = lane >> 4;
        short8 a[4], b[8];
        for (int t = 0; t < 4; t++)
            a[t] = *(const short8*)(As + (wave * 64 + t * 16 + col) * BK + quad * 8);
        for (int t = 0; t < 8; t++)
            b[t] = *(const short8*)(Bs + (t * 16 + col) * BK + quad * 8);
        for (int i = 0; i < 4; i++)
            for (int j = 0; j < 8; j++)
                acc[i][j] = MFMA(a[i], b[j], acc[i][j], 0, 0, 0);
        __syncthreads();
    }
    // epilogue with gating
    int col = lane & 15, quad = lane >> 4;
    for (int mt = 0; mt < 4; mt++) {
        for (int nt = 0; nt < 4; nt++) {
            for (int r = 0; r < 4; r++) {
                int tokg = g * GRP + wave * 64 + mt * 16 + quad * 4 + r;
                int e = e0 + nt * 16 + col;
                float av = acc[mt][nt][r];
                float au = acc[mt][nt + 4][r];
                float v = b2f(hid[(size_t)tokg * HID + e]);
                float u = b2f(hid[(size_t)tokg * HID + 1024 + e]);
                float gate = 1.f / (1.f + __expf(-av * u));
                outg[(size_t)tokg * 1024 + e] = f2b(au * v * gate);
            }
        }
    }
}

// ---------------- qk affine split: quadq/quadk/linq natural + linkT transposed -----------
__global__ __launch_bounds__(256) void qk_affine(
    const bf16* __restrict__ qkb, const float* __restrict__ gamma,
    const float* __restrict__ beta,
    bf16* __restrict__ quadq, bf16* __restrict__ quadk,
    bf16* __restrict__ linq, bf16* __restrict__ linkT, int rowsC)
{
    int t0 = blockIdx.x * 64;
    __shared__ bf16 L[64][DQK + 2];
    int tid = threadIdx.x;
    int d = tid & 127, tl = tid >> 7;
    for (int l = 0; l < 32; l++) {
        int tok = t0 + tl + 2 * l;
        float q = b2f(qkb[(size_t)tok * DQK + d]);
        quadq[(size_t)tok * DQK + d] = f2b(q * gamma[0 * DQK + d] + beta[0 * DQK + d]);
        linq [(size_t)tok * DQK + d] = f2b(q * gamma[1 * DQK + d] + beta[1 * DQK + d]);
        quadk[(size_t)tok * DQK + d] = f2b(q * gamma[2 * DQK + d] + beta[2 * DQK + d]);
        L[tok - t0][d] = f2b(q * gamma[3 * DQK + d] + beta[3 * DQK + d]);
    }
    __syncthreads();
    int dd = tid >> 1, half = tid & 1;
    for (int t = 0; t < 32; t++) {
        int tok = half * 32 + t;
        linkT[(size_t)dd * rowsC + t0 + tok] = L[tok][dd];
    }
}

// ---------------- dwconv (generic, with src stride) + final fp32 variant -----------------
template<typename TO>
__global__ __launch_bounds__(256) void dwconv_res(
    const bf16* __restrict__ src, const float* __restrict__ dw,
    const float* __restrict__ xres, TO* __restrict__ dst, int C, int ldS)
{
    int c0 = blockIdx.x * 64;
    int t0 = blockIdx.y * 64;
    int b  = blockIdx.z;
    __shared__ float s[80][64];
    int tid = threadIdx.x;
    int c = tid & 63;
    int rp = tid >> 6;
    const bf16* base = src + (size_t)b * NN * ldS;
    for (int l = 0; l < 20; l++) {
        int tt = rp + l * 4;
        int t = t0 + tt - 8;
        float v = 0.f;
        if (t >= 0 && t < NN) v = b2f(base[(size_t)t * ldS + c0 + c]);
        s[tt][c] = v;
    }
    __syncthreads();
    float w[KW];
    for (int k = 0; k < KW; k++) w[k] = dw[k * C + c0 + c];
    for (int l = 0; l < 16; l++) {
        int r = rp + l * 4;
        float acc = s[r + 8][c];
        for (int k = 0; k < KW; k++) acc += s[r + k][c] * w[k];
        long gidx = ((long)b * NN + t0 + r) * C + c0 + c;
        if (xres) acc += xres[gidx];
        stv(dst, gidx, acc);
    }
}

// dwconv for h: reads strided src, writes hid [tok][2048] AND hidT [2048][rowsC]
__global__ __launch_bounds__(256) void dwconv_dual(
    const bf16* __restrict__ src, const float* __restrict__ dw,
    bf16* __restrict__ dst, bf16* __restrict__ dstT, int rowsC, int ldS)
{
    int c0 = blockIdx.x * 64, t0 = blockIdx.y * 64, b = blockIdx.z;
    __shared__ float s[80][64];
    __shared__ bf16 o[64][65];
    int tid = threadIdx.x;
    int c = tid & 63, rp = tid >> 6;
    const bf16* base = src + (size_t)b * NN * ldS + c0;
    for (int l = 0; l < 20; l++) {
        int tt = rp + l * 4;
        int t = t0 + tt - 8;
        float v = 0.f;
        if (t >= 0 && t < NN) v = b2f(base[(size_t)t * ldS + c]);
        s[tt][c] = v;
    }
    __syncthreads();
    float w[KW];
    for (int k = 0; k < KW; k++) w[k] = dw[k * HID + c0 + c];
    for (int l = 0; l < 16; l++) {
        int r = rp + l * 4;
        float acc = s[r + 8][c];
        for (int k = 0; k < KW; k++) acc += s[r + k][c] * w[k];
        bf16 hv = f2b(acc);
        dst[((size_t)b * NN + t0 + r) * HID + c0 + c] = hv;
        o[c][r] = hv;
    }
    __syncthreads();
    int ch = tid >> 2, seg = tid & 3;
    for (int t = 0; t < 16; t++) {
        int tok = seg * 16 + t;
        dstT[(size_t)(c0 + ch) * rowsC + b * NN + t0 + tok] = o[ch][tok];
    }
}

extern "C" void kernel_launch(void* const* d_in, const int* in_sizes, int n_in,
                              void* d_out, int out_size, void* d_ws, size_t ws_size,
                              hipStream_t stream)
{
    const float* x      = (const float*)d_in[0];
    const float* ln_h_g = (const float*)d_in[1];
    const float* ln_h_b = (const float*)d_in[2];
    const float* W_h    = (const float*)d_in[3];
    const float* b_h    = (const float*)d_in[4];
    const float* dw_h   = (const float*)d_in[5];
    const float* ln_qk_g= (const float*)d_in[6];
    const float* ln_qk_b= (const float*)d_in[7];
    const float* W_qk   = (const float*)d_in[8];
    const float* b_qk   = (const float*)d_in[9];
    const float* dw_qk  = (const float*)d_in[10];
    const float* gamma  = (const float*)d_in[11];
    const float* beta   = (const float*)d_in[12];
    const float* ln_o_g = (const float*)d_in[13];
    const float* ln_o_b = (const float*)d_in[14];
    const float* W_o    = (const float*)d_in[15];
    const float* b_o    = (const float*)d_in[16];
    const float* dw_o   = (const float*)d_in[17];
    float* outp = (float*)d_out;

    // ---- fixed region: WT_h and WT_qk CONTIGUOUS ([2176][512]); biases contiguous too ----
    char* p = (char*)d_ws;
    bf16* WT_hq = (bf16*)p;  p += (size_t)NHQ * DIM * 2;        // rows 0..2047 = h, 2048.. = qk
    bf16* WT_o  = (bf16*)p;  p += (size_t)DIM * 1024 * 2;
    float* bias_hq = (float*)p; p += NHQ * 4;                   // [0..2047]=h, [2048..]=qk
    float* bias_o  = (float*)p; p += DIM * 4;
    p = (char*)(((uintptr_t)p + 255) & ~(uintptr_t)255);
    size_t fixed = (size_t)(p - (char*)d_ws);
    bf16* WT_h  = WT_hq;
    bf16* WT_qk = WT_hq + (size_t)HID * DIM;
    float* bias_h  = bias_hq;
    float* bias_qk = bias_hq + HID;

    auto bytes_for = [fixed](int cb) -> size_t {
        size_t rows = (size_t)cb * NN;
        return fixed
             + rows * NHQ * 2                 // s1: hq -> linkvT(fp32, smaller) -> fin_pre
             + rows * HID * 2                 // s2: hid -> hat2
             + rows * HID * 2                 // s3: hidT
             + rows * 1024 * 2                // s4: outg
             + rows * DIM * 2                 // s5: hat1 -> P
             + 5 * rows * DQK * 2             // s6..s10
             + rows * 1024 * 2                // s11: linkvb
             + 4096;
    };
    int CB = 1;
    if (bytes_for(4) <= ws_size) CB = 4;
    else if (bytes_for(2) <= ws_size) CB = 2;
    const int rowsC = CB * NN;
    const size_t rows = (size_t)rowsC;

    char* s1 = p;               p += rows * NHQ * 2;   // hq -> linkvT -> fin_pre
    char* s2 = p;               p += rows * HID * 2;   // hid -> hat2
    char* s3 = p;               p += rows * HID * 2;   // hidT
    char* s4 = p;               p += rows * 1024 * 2;  // outg
    char* s5 = p;               p += rows * DIM * 2;   // hat1 -> P
    char* s6 = p;               p += rows * DQK * 2;   // linkT
    char* s7 = p;               p += rows * DQK * 2;   // qkb
    char* s8 = p;               p += rows * DQK * 2;   // quadq
    char* s9 = p;               p += rows * DQK * 2;   // quadk
    char* s10 = p;              p += rows * DQK * 2;   // linq
    char* s11 = p;              p += rows * 1024 * 2;  // linkvb (bf16 cumsum out)

    bf16*  hq      = (bf16*)s1;   // [rows][2176]: h cols 0..2047, qk cols 2048..2175
    float* linkvT  = (float*)s1;
    bf16*  fin_pre = (bf16*)s1;
    bf16*  hid     = (bf16*)s2;
    bf16*  hat2    = (bf16*)s2;
    bf16*  hidT    = (bf16*)s3;
    bf16*  outg    = (bf16*)s4;
    bf16*  hat1    = (bf16*)s5;
    bf16*  P       = (bf16*)s5;
    bf16*  linkT   = (bf16*)s6;
    bf16*  qkb     = (bf16*)s7;
    bf16*  quadq   = (bf16*)s8;
    bf16*  quadk   = (bf16*)s9;
    bf16*  linq    = (bf16*)s10;
    bf16*  linkvb  = (bf16*)s11;

    // ---- weight prep (fold LN affine into weights/biases) ----
    prep_wT<<<dim3(DIM / 32, HID / 32), 256, 0, stream>>>(W_h, ln_h_g, WT_h, DIM, HID);
    prep_wT<<<dim3(DIM / 32, DQK / 32), 256, 0, stream>>>(W_qk, ln_qk_g, WT_qk, DIM, DQK);
    prep_wT<<<dim3(1024 / 32, DIM / 32), 256, 0, stream>>>(W_o, ln_o_g, WT_o, 1024, DIM);
    bias_init<<<HID / 256, 256, 0, stream>>>(b_h, bias_h, HID);
    bias_init<<<1, 256, 0, stream>>>(b_qk, bias_qk, DQK);
    bias_init<<<2, 256, 0, stream>>>(b_o, bias_o, DIM);
    bias_reduce<<<dim3(HID / 256, DIM / BKC), 256, 0, stream>>>(W_h, ln_h_b, bias_h, DIM, HID);
    bias_reduce<<<dim3(1, DIM / BKC), 256, 0, stream>>>(W_qk, ln_qk_b, bias_qk, DIM, DQK);
    bias_reduce<<<dim3(2, 1024 / BKC), 256, 0, stream>>>(W_o, ln_o_b, bias_o, 1024, DIM);

    const int G = CB * NG;   // groups per chunk
    for (int b0 = 0; b0 < BB; b0 += CB) {
        const float* xc = x    + (size_t)b0 * NN * DIM;
        float* outc     = outp + (size_t)b0 * NN * DIM;
        int R = rowsC;

        // 1) LN of token-shifted x -> hat1
        ln_kernel<float, DIM, 1><<<R, 256, 0, stream>>>(xc, hat1);
        // 2) merged gemm: hq[.,0..2047]=h, hq[.,2048..2175]=qk_pre (both silu)
        gemm_mfma<<<dim3(NHQ / 128, R / 128), 256, 0, stream>>>(
            hat1, WT_hq, bias_hq, hq, R, NHQ, DIM, NHQ);
        // 3) hid + hidT = h + dwconv(h)  (reads hq with stride 2176)
        dwconv_dual<<<dim3(HID / 64, NN / 64, CB), 256, 0, stream>>>(hq, dw_h, hid, hidT, rowsC, NHQ);
        // 4) qkb = qk_pre + dwconv(qk_pre)  (reads hq+2048 with stride 2176)
        dwconv_res<bf16><<<dim3(DQK / 64, NN / 64, CB), 256, 0, stream>>>(
            hq + HID, dw_qk, nullptr, qkb, DQK, NHQ);
        // 5) qk affine -> quadq/quadk/linq (natural) + linkT (transposed)
        qk_affine<<<R / 64, 256, 0, stream>>>(qkb, gamma, beta, quadq, quadk, linq, linkT, rowsC);
        // 6) quadratic scores -> P (bf16)  (hq dead; s1 free for linkvT)
        attn_score_mfma<<<dim3(2, 2, G), 256, 0, stream>>>(quadq, quadk, P);
        // 7) linear attention kv -> linkvT [g][e][d] fp32 (s1)
        linkv_mfma<<<dim3(1, HID / 128, G), 256, 0, stream>>>(hidT, linkT, linkvT, rowsC);
        // 8) exclusive cumsum over groups -> linkvb bf16 (s11)
        cumsum_bf<<<(CB * DQK * HID) / 256, 256, 0, stream>>>(linkvT, linkvb);
        // 9) fused apply + gating -> outg (256-token blocks)
        attn_apply_mfma<<<dim3(16, G), 256, 0, stream>>>(P, hidT, linq, linkvb, hid, outg, rowsC);
        // 10) LN(outg) -> hat2
        ln_kernel_bf<1024><<<R, 256, 0, stream>>>(outg, hat2);
        // 11) fin_pre = silu(hat2 @ W_o' + bias_o')  (s1; linkvT dead)
        gemm_mfma<<<dim3(DIM / 128, R / 128), 256, 0, stream>>>(
            hat2, WT_o, bias_o, fin_pre, R, DIM, 1024, DIM);
        // 12) d_out(fp32) = x + fin_pre + dwconv(fin_pre)
        dwconv_res<float><<<dim3(DIM / 64, NN / 64, CB), 256, 0, stream>>>(
            fin_pre, dw_o, xc, outc, DIM, DIM);
    }
}

// Round 10
// 583.135 us; speedup vs baseline: 4.8205x; 1.0329x over previous
//
#include <hip/hip_runtime.h>
#include <hip/hip_bf16.h>

typedef __hip_bfloat16 bf16;
typedef __attribute__((ext_vector_type(8))) short short8;
typedef __attribute__((ext_vector_type(4))) float float4v;
__device__ __forceinline__ float b2f(bf16 v){ return __bfloat162float(v); }
__device__ __forceinline__ bf16 f2b(float v){ return __float2bfloat16(v); }
__device__ __forceinline__ void stv(float* p, long i, float v){ p[i] = v; }
__device__ __forceinline__ void stv(bf16*  p, long i, float v){ p[i] = f2b(v); }

#define MFMA __builtin_amdgcn_mfma_f32_16x16x32_bf16
#define AS1(p) ((const __attribute__((address_space(1))) void*)(p))
#define AS3(p) ((__attribute__((address_space(3))) void*)(p))

// Problem constants
#define BB   8
#define NN   2048
#define DIM  512
#define HID  2048
#define DQK  128
#define GRP  256
#define NG   8
#define KW   17
#define BK   32
#define NHQ  2176   // merged N for h(2048) + qk(128) gemm

// ---------------- LayerNorm (token-shift variant for x, plain bf16 variant) ------------
template<typename TI, int D, int SHIFT_HALF>
__global__ __launch_bounds__(256) void ln_kernel(const TI* __restrict__ in,
                                                 bf16* __restrict__ out)
{
    int row = blockIdx.x;
    int t = row % NN;
    int tid = threadIdx.x;
    const int PT = D / 256;
    float vals[PT];
    float s = 0.f, ss = 0.f;
    for (int i = 0; i < PT; i++) {
        int c = tid + i * 256;
        float v;
        if (SHIFT_HALF && c < D / 2) {
            v = (t > 0) ? (float)(in[((long)row - 1) * D + c]) : 0.f;
        } else {
            v = (float)(in[(long)row * D + c]);
        }
        vals[i] = v; s += v; ss += v * v;
    }
    for (int o = 32; o > 0; o >>= 1) { s += __shfl_down(s, o); ss += __shfl_down(ss, o); }
    __shared__ float sm[4], sm2[4];
    int wid = tid >> 6, lane = tid & 63;
    if (lane == 0) { sm[wid] = s; sm2[wid] = ss; }
    __syncthreads();
    if (tid == 0) {
        float a = 0.f, q = 0.f;
        for (int w = 0; w < 4; w++) { a += sm[w]; q += sm2[w]; }
        sm[0] = a; sm2[0] = q;
    }
    __syncthreads();
    float mean = sm[0] / D;
    float var  = fmaxf(sm2[0] / D - mean * mean, 0.f);
    float rs = rsqrtf(var + 1e-5f);
    for (int i = 0; i < PT; i++) {
        int c = tid + i * 256;
        out[(long)row * D + c] = f2b((vals[i] - mean) * rs);
    }
}

template<int D>
__global__ __launch_bounds__(256) void ln_kernel_bf(const bf16* __restrict__ in,
                                                    bf16* __restrict__ out)
{
    int row = blockIdx.x;
    int tid = threadIdx.x;
    const int PT = D / 256;
    float vals[PT];
    float s = 0.f, ss = 0.f;
    for (int i = 0; i < PT; i++) {
        int c = tid + i * 256;
        float v = b2f(in[(long)row * D + c]);
        vals[i] = v; s += v; ss += v * v;
    }
    for (int o = 32; o > 0; o >>= 1) { s += __shfl_down(s, o); ss += __shfl_down(ss, o); }
    __shared__ float sm[4], sm2[4];
    int wid = tid >> 6, lane = tid & 63;
    if (lane == 0) { sm[wid] = s; sm2[wid] = ss; }
    __syncthreads();
    if (tid == 0) {
        float a = 0.f, q = 0.f;
        for (int w = 0; w < 4; w++) { a += sm[w]; q += sm2[w]; }
        sm[0] = a; sm2[0] = q;
    }
    __syncthreads();
    float mean = sm[0] / D;
    float var  = fmaxf(sm2[0] / D - mean * mean, 0.f);
    float rs = rsqrtf(var + 1e-5f);
    for (int i = 0; i < PT; i++) {
        int c = tid + i * 256;
        out[(long)row * D + c] = f2b((vals[i] - mean) * rs);
    }
}

// ---------------- weight prep: WT[n][k] = bf16(g[k]*W[k][n]) -----------------------------
__global__ __launch_bounds__(256) void prep_wT(const float* __restrict__ W,
                                               const float* __restrict__ g,
                                               bf16* __restrict__ WT, int K, int N)
{
    int k0 = blockIdx.x * 32, n0 = blockIdx.y * 32;
    __shared__ float Ws[32][33];
    int tid = threadIdx.x;
    for (int l = 0; l < 4; l++) {
        int e = tid + 256 * l;
        int kk = e >> 5, nn = e & 31;
        Ws[kk][nn] = g[k0 + kk] * W[(size_t)(k0 + kk) * N + n0 + nn];
    }
    __syncthreads();
    for (int l = 0; l < 4; l++) {
        int e = tid + 256 * l;
        int nn = e >> 5, kk = e & 31;
        WT[(size_t)(n0 + nn) * K + k0 + kk] = f2b(Ws[kk][nn]);
    }
}

// ---------------- fused bias: out = b; out += lnb @ W ------------------------------------
__global__ __launch_bounds__(256) void bias_init(const float* __restrict__ b,
                                                 float* __restrict__ out, int N)
{
    int n = blockIdx.x * 256 + threadIdx.x;
    if (n < N) out[n] = b[n];
}

#define BKC 64
__global__ __launch_bounds__(256) void bias_reduce(const float* __restrict__ W,
                                                   const float* __restrict__ lnb,
                                                   float* __restrict__ out, int K, int N)
{
    int n = blockIdx.x * 256 + threadIdx.x;
    int k0 = blockIdx.y * BKC;
    if (n >= N) return;
    float s = 0.f;
    #pragma unroll 8
    for (int k = k0; k < k0 + BKC; k++) s += lnb[k] * W[(size_t)k * N + n];
    atomicAdd(&out[n], s);
}

// ---------------- staging helper: 128 rows x 32 cols bf16 tile via global_load_lds -------
__device__ __forceinline__ void stage_tile(const bf16* base, size_t ld, bf16* dst,
                                           int wave, int lane)
{
    int lrow = lane >> 2, lcol = lane & 3;
    for (int cc = 0; cc < 2; cc++) {
        int c = wave * 2 + cc;
        int row = c * 16 + lrow;
        const bf16* g = base + (size_t)row * ld + lcol * 8;
        __builtin_amdgcn_global_load_lds(AS1(g), AS3(dst + c * 512), 16, 0, 0);
    }
}

// ---------------- MFMA GEMM: C = silu(A@B^T + bias); BK=64 via dual 32-col sub-buffers ---
__global__ __launch_bounds__(256) void gemm_mfma(
    const bf16* __restrict__ A, const bf16* __restrict__ BT,
    const float* __restrict__ bias, bf16* __restrict__ C,
    int M, int N, int K, int ldC)
{
    __shared__ bf16 As[2][128 * BK];
    __shared__ bf16 Bs[2][128 * BK];
    int n0 = blockIdx.x * 128, m0 = blockIdx.y * 128;
    int tid = threadIdx.x, wave = tid >> 6, lane = tid & 63;
    int wm = wave & 1, wn = wave >> 1;
    float4v acc[4][4] = {};
    for (int k0 = 0; k0 < K; k0 += 2 * BK) {
        stage_tile(A  + (size_t)m0 * K + k0,      K, As[0], wave, lane);
        stage_tile(A  + (size_t)m0 * K + k0 + BK, K, As[1], wave, lane);
        stage_tile(BT + (size_t)n0 * K + k0,      K, Bs[0], wave, lane);
        stage_tile(BT + (size_t)n0 * K + k0 + BK, K, Bs[1], wave, lane);
        __syncthreads();
        int col = lane & 15, quad = lane >> 4;
        for (int s = 0; s < 2; s++) {
            short8 a[4], b[4];
            for (int t = 0; t < 4; t++) {
                a[t] = *(const short8*)(As[s] + (wm * 64 + t * 16 + col) * BK + quad * 8);
                b[t] = *(const short8*)(Bs[s] + (wn * 64 + t * 16 + col) * BK + quad * 8);
            }
            for (int i = 0; i < 4; i++)
                for (int j = 0; j < 4; j++)
                    acc[i][j] = MFMA(a[i], b[j], acc[i][j], 0, 0, 0);
        }
        __syncthreads();
    }
    int col = lane & 15, quad = lane >> 4;
    for (int i = 0; i < 4; i++) {
        for (int j = 0; j < 4; j++) {
            int n = n0 + wn * 64 + j * 16 + col;
            float bs = bias[n];
            for (int r = 0; r < 4; r++) {
                int m = m0 + wm * 64 + i * 16 + quad * 4 + r;
                float v = acc[i][j][r] + bs;
                v = v / (1.f + __expf(-v));
                C[(size_t)m * ldC + n] = f2b(v);
            }
        }
    }
}

// ---------------- attn scores MFMA: P = relu(QK^T/256)^2, causal, bf16 (BK=64) ----------
__global__ __launch_bounds__(256) void attn_score_mfma(
    const bf16* __restrict__ quadq, const bf16* __restrict__ quadk,
    bf16* __restrict__ P)
{
    int g = blockIdx.z, bi = blockIdx.y, bj = blockIdx.x;
    bf16* Pg = P + (size_t)g * GRP * GRP;
    int tid = threadIdx.x;
    if (bj > bi) {   // fully masked tile: write zeros
        short8 z = {};
        int rr = tid >> 1, half = tid & 1;
        short* dst = (short*)Pg + (size_t)(bi * 128 + rr) * GRP + bj * 128 + half * 64;
        for (int q = 0; q < 8; q++) ((short8*)dst)[q] = z;
        return;
    }
    __shared__ bf16 As[2][128 * BK];
    __shared__ bf16 Bs[2][128 * BK];
    int wave = tid >> 6, lane = tid & 63;
    int wm = wave & 1, wn = wave >> 1;
    float4v acc[4][4] = {};
    const bf16* Ab = quadq + (size_t)(g * GRP + bi * 128) * DQK;
    const bf16* Bb = quadk + (size_t)(g * GRP + bj * 128) * DQK;
    for (int k0 = 0; k0 < DQK; k0 += 2 * BK) {
        stage_tile(Ab + k0,      DQK, As[0], wave, lane);
        stage_tile(Ab + k0 + BK, DQK, As[1], wave, lane);
        stage_tile(Bb + k0,      DQK, Bs[0], wave, lane);
        stage_tile(Bb + k0 + BK, DQK, Bs[1], wave, lane);
        __syncthreads();
        int col = lane & 15, quad = lane >> 4;
        for (int s = 0; s < 2; s++) {
            short8 a[4], b[4];
            for (int t = 0; t < 4; t++) {
                a[t] = *(const short8*)(As[s] + (wm * 64 + t * 16 + col) * BK + quad * 8);
                b[t] = *(const short8*)(Bs[s] + (wn * 64 + t * 16 + col) * BK + quad * 8);
            }
            for (int i = 0; i < 4; i++)
                for (int j = 0; j < 4; j++)
                    acc[i][j] = MFMA(a[i], b[j], acc[i][j], 0, 0, 0);
        }
        __syncthreads();
    }
    int col = lane & 15, quad = lane >> 4;
    for (int i = 0; i < 4; i++) {
        for (int j = 0; j < 4; j++) {
            int jj = bj * 128 + wn * 64 + j * 16 + col;
            for (int r = 0; r < 4; r++) {
                int ii = bi * 128 + wm * 64 + i * 16 + quad * 4 + r;
                float s = acc[i][j][r] * (1.f / GRP);
                s = fmaxf(s, 0.f); s = s * s;
                if (jj > ii) s = 0.f;
                Pg[(size_t)ii * GRP + jj] = f2b(s);
            }
        }
    }
}

// ---------------- linkv MFMA: linkvT[g][e][d] = (hidT_g @ linkT_g^T)/256 (BK=64) --------
__global__ __launch_bounds__(256) void linkv_mfma(
    const bf16* __restrict__ hidT, const bf16* __restrict__ linkT,
    float* __restrict__ linkvT, int rowsC)
{
    int g = blockIdx.z, eb = blockIdx.y;
    int e0 = eb * 128;
    __shared__ bf16 As[2][128 * BK];
    __shared__ bf16 Bs[2][128 * BK];
    int tid = threadIdx.x, wave = tid >> 6, lane = tid & 63;
    int wm = wave & 1, wn = wave >> 1;
    float4v acc[4][4] = {};
    for (int k0 = 0; k0 < GRP; k0 += 2 * BK) {
        stage_tile(hidT  + (size_t)e0 * rowsC + g * GRP + k0,      rowsC, As[0], wave, lane);
        stage_tile(hidT  + (size_t)e0 * rowsC + g * GRP + k0 + BK, rowsC, As[1], wave, lane);
        stage_tile(linkT + g * GRP + k0,      rowsC, Bs[0], wave, lane);
        stage_tile(linkT + g * GRP + k0 + BK, rowsC, Bs[1], wave, lane);
        __syncthreads();
        int col = lane & 15, quad = lane >> 4;
        for (int s = 0; s < 2; s++) {
            short8 a[4], b[4];
            for (int t = 0; t < 4; t++) {
                a[t] = *(const short8*)(As[s] + (wm * 64 + t * 16 + col) * BK + quad * 8);
                b[t] = *(const short8*)(Bs[s] + (wn * 64 + t * 16 + col) * BK + quad * 8);
            }
            for (int i = 0; i < 4; i++)
                for (int j = 0; j < 4; j++)
                    acc[i][j] = MFMA(a[i], b[j], acc[i][j], 0, 0, 0);
        }
        __syncthreads();
    }
    float* out = linkvT + (size_t)g * (HID * DQK);
    int col = lane & 15, quad = lane >> 4;
    for (int i = 0; i < 4; i++) {
        for (int j = 0; j < 4; j++) {
            int d = wn * 64 + j * 16 + col;
            for (int r = 0; r < 4; r++) {
                int e = e0 + wm * 64 + i * 16 + quad * 4 + r;
                out[(size_t)e * DQK + d] = acc[i][j][r] * (1.f / GRP);
            }
        }
    }
}

// ---------------- exclusive cumsum over group axis, fp32 in -> bf16 out -----------------
__global__ void cumsum_bf(const float* __restrict__ in, bf16* __restrict__ out)
{
    long idx = (long)blockIdx.x * blockDim.x + threadIdx.x;
    int b = (int)(idx / (DQK * HID));
    long off = idx % (DQK * HID);
    const float* pi = in + (long)b * NG * DQK * HID + off;
    bf16* po = out + (long)b * NG * DQK * HID + off;
    float run = 0.f;
    for (int gi = 0; gi < NG; gi++) {
        po[(long)gi * DQK * HID] = f2b(run);
        run += pi[(long)gi * DQK * HID];
    }
}

// ---------------- fused attn apply MFMA + gating (256-token blocks) ----------------------
__global__ __launch_bounds__(256) void attn_apply_mfma(
    const bf16* __restrict__ P, const bf16* __restrict__ hidT,
    const bf16* __restrict__ linq, const bf16* __restrict__ linkvb,
    const bf16* __restrict__ hid, bf16* __restrict__ outg, int rowsC)
{
    int g = blockIdx.y, e0 = blockIdx.x * 64;
    __shared__ bf16 As[256 * BK];
    __shared__ bf16 Bs[128 * BK];
    int tid = threadIdx.x, wave = tid >> 6, lane = tid & 63;
    int lrow = lane >> 2, lcol = lane & 3;
    float4v acc[4][8] = {};
    const bf16* Pg = P + (size_t)g * GRP * GRP;
    // phase 1: quadratic, K = 256 over j
    for (int j0 = 0; j0 < GRP; j0 += BK) {
        for (int cc = 0; cc < 4; cc++) {
            int c = wave * 4 + cc;
            int row = c * 16 + lrow;
            const bf16* ga = Pg + (size_t)row * GRP + j0 + lcol * 8;
            __builtin_amdgcn_global_load_lds(AS1(ga), AS3(As + c * 512), 16, 0, 0);
        }
        for (int cc = 0; cc < 2; cc++) {
            int c = wave * 2 + cc;
            int row = c * 16 + lrow;
            int er = (row < 64) ? (e0 + row) : (1024 + e0 + (row - 64));
            const bf16* gb = hidT + (size_t)er * rowsC + g * GRP + j0 + lcol * 8;
            __builtin_amdgcn_global_load_lds(AS1(gb), AS3(Bs + c * 512), 16, 0, 0);
        }
        __syncthreads();
        int col = lane & 15, quad = lane >> 4;
        short8 a[4], b[8];
        for (int t = 0; t < 4; t++)
            a[t] = *(const short8*)(As + (wave * 64 + t * 16 + col) * BK + quad * 8);
        for (int t = 0; t < 8; t++)
            b[t] = *(const short8*)(Bs + (t * 16 + col) * BK + quad * 8);
        for (int i = 0; i < 4; i++)
            for (int j = 0; j < 8; j++)
                acc[i][j] = MFMA(a[i], b[j], acc[i][j], 0, 0, 0);
        __syncthreads();
    }
    // phase 2: linear, K = 128 over d
    const bf16* Lg = linkvb + (size_t)g * (HID * DQK);
    for (int d0 = 0; d0 < DQK; d0 += BK) {
        for (int cc = 0; cc < 4; cc++) {
            int c = wave * 4 + cc;
            int row = c * 16 + lrow;
            const bf16* ga = linq + (size_t)(g * GRP + row) * DQK + d0 + lcol * 8;
            __builtin_amdgcn_global_load_lds(AS1(ga), AS3(As + c * 512), 16, 0, 0);
        }
        for (int cc = 0; cc < 2; cc++) {
            int c = wave * 2 + cc;
            int row = c * 16 + lrow;
            int er = (row < 64) ? (e0 + row) : (1024 + e0 + (row - 64));
            const bf16* gb = Lg + (size_t)er * DQK + d0 + lcol * 8;
            __builtin_amdgcn_global_load_lds(AS1(gb), AS3(Bs + c * 512), 16, 0, 0);
        }
        __syncthreads();
        int col = lane & 15, quad = lane >> 4;
        short8 a[4], b[8];
        for (int t = 0; t < 4; t++)
            a[t] = *(const short8*)(As + (wave * 64 + t * 16 + col) * BK + quad * 8);
        for (int t = 0; t < 8; t++)
            b[t] = *(const short8*)(Bs + (t * 16 + col) * BK + quad * 8);
        for (int i = 0; i < 4; i++)
            for (int j = 0; j < 8; j++)
                acc[i][j] = MFMA(a[i], b[j], acc[i][j], 0, 0, 0);
        __syncthreads();
    }
    // epilogue with gating
    int col = lane & 15, quad = lane >> 4;
    for (int mt = 0; mt < 4; mt++) {
        for (int nt = 0; nt < 4; nt++) {
            for (int r = 0; r < 4; r++) {
                int tokg = g * GRP + wave * 64 + mt * 16 + quad * 4 + r;
                int e = e0 + nt * 16 + col;
                float av = acc[mt][nt][r];
                float au = acc[mt][nt + 4][r];
                float v = b2f(hid[(size_t)tokg * HID + e]);
                float u = b2f(hid[(size_t)tokg * HID + 1024 + e]);
                float gate = 1.f / (1.f + __expf(-av * u));
                outg[(size_t)tokg * 1024 + e] = f2b(au * v * gate);
            }
        }
    }
}

// ---------------- qk affine split: quadq/quadk/linq natural + linkT transposed -----------
__global__ __launch_bounds__(256) void qk_affine(
    const bf16* __restrict__ qkb, const float* __restrict__ gamma,
    const float* __restrict__ beta,
    bf16* __restrict__ quadq, bf16* __restrict__ quadk,
    bf16* __restrict__ linq, bf16* __restrict__ linkT, int rowsC)
{
    int t0 = blockIdx.x * 64;
    __shared__ bf16 L[64][DQK + 2];
    int tid = threadIdx.x;
    int d = tid & 127, tl = tid >> 7;
    for (int l = 0; l < 32; l++) {
        int tok = t0 + tl + 2 * l;
        float q = b2f(qkb[(size_t)tok * DQK + d]);
        quadq[(size_t)tok * DQK + d] = f2b(q * gamma[0 * DQK + d] + beta[0 * DQK + d]);
        linq [(size_t)tok * DQK + d] = f2b(q * gamma[1 * DQK + d] + beta[1 * DQK + d]);
        quadk[(size_t)tok * DQK + d] = f2b(q * gamma[2 * DQK + d] + beta[2 * DQK + d]);
        L[tok - t0][d] = f2b(q * gamma[3 * DQK + d] + beta[3 * DQK + d]);
    }
    __syncthreads();
    int dd = tid >> 1, half = tid & 1;
    for (int t = 0; t < 32; t++) {
        int tok = half * 32 + t;
        linkT[(size_t)dd * rowsC + t0 + tok] = L[tok][dd];
    }
}

// ---------------- dwconv (generic, with src stride) + final fp32 variant -----------------
template<typename TO>
__global__ __launch_bounds__(256) void dwconv_res(
    const bf16* __restrict__ src, const float* __restrict__ dw,
    const float* __restrict__ xres, TO* __restrict__ dst, int C, int ldS)
{
    int c0 = blockIdx.x * 64;
    int t0 = blockIdx.y * 64;
    int b  = blockIdx.z;
    __shared__ float s[80][64];
    int tid = threadIdx.x;
    int c = tid & 63;
    int rp = tid >> 6;
    const bf16* base = src + (size_t)b * NN * ldS;
    for (int l = 0; l < 20; l++) {
        int tt = rp + l * 4;
        int t = t0 + tt - 8;
        float v = 0.f;
        if (t >= 0 && t < NN) v = b2f(base[(size_t)t * ldS + c0 + c]);
        s[tt][c] = v;
    }
    __syncthreads();
    float w[KW];
    for (int k = 0; k < KW; k++) w[k] = dw[k * C + c0 + c];
    for (int l = 0; l < 16; l++) {
        int r = rp + l * 4;
        float acc = s[r + 8][c];
        for (int k = 0; k < KW; k++) acc += s[r + k][c] * w[k];
        long gidx = ((long)b * NN + t0 + r) * C + c0 + c;
        if (xres) acc += xres[gidx];
        stv(dst, gidx, acc);
    }
}

// dwconv for h: reads strided src, writes hid [tok][2048] AND hidT [2048][rowsC]
__global__ __launch_bounds__(256) void dwconv_dual(
    const bf16* __restrict__ src, const float* __restrict__ dw,
    bf16* __restrict__ dst, bf16* __restrict__ dstT, int rowsC, int ldS)
{
    int c0 = blockIdx.x * 64, t0 = blockIdx.y * 64, b = blockIdx.z;
    __shared__ float s[80][64];
    __shared__ bf16 o[64][65];
    int tid = threadIdx.x;
    int c = tid & 63, rp = tid >> 6;
    const bf16* base = src + (size_t)b * NN * ldS + c0;
    for (int l = 0; l < 20; l++) {
        int tt = rp + l * 4;
        int t = t0 + tt - 8;
        float v = 0.f;
        if (t >= 0 && t < NN) v = b2f(base[(size_t)t * ldS + c]);
        s[tt][c] = v;
    }
    __syncthreads();
    float w[KW];
    for (int k = 0; k < KW; k++) w[k] = dw[k * HID + c0 + c];
    for (int l = 0; l < 16; l++) {
        int r = rp + l * 4;
        float acc = s[r + 8][c];
        for (int k = 0; k < KW; k++) acc += s[r + k][c] * w[k];
        bf16 hv = f2b(acc);
        dst[((size_t)b * NN + t0 + r) * HID + c0 + c] = hv;
        o[c][r] = hv;
    }
    __syncthreads();
    int ch = tid >> 2, seg = tid & 3;
    for (int t = 0; t < 16; t++) {
        int tok = seg * 16 + t;
        dstT[(size_t)(c0 + ch) * rowsC + b * NN + t0 + tok] = o[ch][tok];
    }
}

extern "C" void kernel_launch(void* const* d_in, const int* in_sizes, int n_in,
                              void* d_out, int out_size, void* d_ws, size_t ws_size,
                              hipStream_t stream)
{
    const float* x      = (const float*)d_in[0];
    const float* ln_h_g = (const float*)d_in[1];
    const float* ln_h_b = (const float*)d_in[2];
    const float* W_h    = (const float*)d_in[3];
    const float* b_h    = (const float*)d_in[4];
    const float* dw_h   = (const float*)d_in[5];
    const float* ln_qk_g= (const float*)d_in[6];
    const float* ln_qk_b= (const float*)d_in[7];
    const float* W_qk   = (const float*)d_in[8];
    const float* b_qk   = (const float*)d_in[9];
    const float* dw_qk  = (const float*)d_in[10];
    const float* gamma  = (const float*)d_in[11];
    const float* beta   = (const float*)d_in[12];
    const float* ln_o_g = (const float*)d_in[13];
    const float* ln_o_b = (const float*)d_in[14];
    const float* W_o    = (const float*)d_in[15];
    const float* b_o    = (const float*)d_in[16];
    const float* dw_o   = (const float*)d_in[17];
    float* outp = (float*)d_out;

    // ---- fixed region: WT_h and WT_qk CONTIGUOUS ([2176][512]); biases contiguous too ----
    char* p = (char*)d_ws;
    bf16* WT_hq = (bf16*)p;  p += (size_t)NHQ * DIM * 2;
    bf16* WT_o  = (bf16*)p;  p += (size_t)DIM * 1024 * 2;
    float* bias_hq = (float*)p; p += NHQ * 4;
    float* bias_o  = (float*)p; p += DIM * 4;
    p = (char*)(((uintptr_t)p + 255) & ~(uintptr_t)255);
    size_t fixed = (size_t)(p - (char*)d_ws);
    bf16* WT_h  = WT_hq;
    bf16* WT_qk = WT_hq + (size_t)HID * DIM;
    float* bias_h  = bias_hq;
    float* bias_qk = bias_hq + HID;

    auto bytes_for = [fixed](int cb) -> size_t {
        size_t rows = (size_t)cb * NN;
        return fixed
             + rows * NHQ * 2
             + rows * HID * 2
             + rows * HID * 2
             + rows * 1024 * 2
             + rows * DIM * 2
             + 5 * rows * DQK * 2
             + rows * 1024 * 2
             + 4096;
    };
    int CB = 1;
    if (bytes_for(4) <= ws_size) CB = 4;
    else if (bytes_for(2) <= ws_size) CB = 2;
    const int rowsC = CB * NN;
    const size_t rows = (size_t)rowsC;

    char* s1 = p;               p += rows * NHQ * 2;   // hq -> linkvT -> fin_pre
    char* s2 = p;               p += rows * HID * 2;   // hid -> hat2
    char* s3 = p;               p += rows * HID * 2;   // hidT
    char* s4 = p;               p += rows * 1024 * 2;  // outg
    char* s5 = p;               p += rows * DIM * 2;   // hat1 -> P
    char* s6 = p;               p += rows * DQK * 2;   // linkT
    char* s7 = p;               p += rows * DQK * 2;   // qkb
    char* s8 = p;               p += rows * DQK * 2;   // quadq
    char* s9 = p;               p += rows * DQK * 2;   // quadk
    char* s10 = p;              p += rows * DQK * 2;   // linq
    char* s11 = p;              p += rows * 1024 * 2;  // linkvb (bf16 cumsum out)

    bf16*  hq      = (bf16*)s1;
    float* linkvT  = (float*)s1;
    bf16*  fin_pre = (bf16*)s1;
    bf16*  hid     = (bf16*)s2;
    bf16*  hat2    = (bf16*)s2;
    bf16*  hidT    = (bf16*)s3;
    bf16*  outg    = (bf16*)s4;
    bf16*  hat1    = (bf16*)s5;
    bf16*  P       = (bf16*)s5;
    bf16*  linkT   = (bf16*)s6;
    bf16*  qkb     = (bf16*)s7;
    bf16*  quadq   = (bf16*)s8;
    bf16*  quadk   = (bf16*)s9;
    bf16*  linq    = (bf16*)s10;
    bf16*  linkvb  = (bf16*)s11;

    // ---- weight prep (fold LN affine into weights/biases) ----
    prep_wT<<<dim3(DIM / 32, HID / 32), 256, 0, stream>>>(W_h, ln_h_g, WT_h, DIM, HID);
    prep_wT<<<dim3(DIM / 32, DQK / 32), 256, 0, stream>>>(W_qk, ln_qk_g, WT_qk, DIM, DQK);
    prep_wT<<<dim3(1024 / 32, DIM / 32), 256, 0, stream>>>(W_o, ln_o_g, WT_o, 1024, DIM);
    bias_init<<<HID / 256, 256, 0, stream>>>(b_h, bias_h, HID);
    bias_init<<<1, 256, 0, stream>>>(b_qk, bias_qk, DQK);
    bias_init<<<2, 256, 0, stream>>>(b_o, bias_o, DIM);
    bias_reduce<<<dim3(HID / 256, DIM / BKC), 256, 0, stream>>>(W_h, ln_h_b, bias_h, DIM, HID);
    bias_reduce<<<dim3(1, DIM / BKC), 256, 0, stream>>>(W_qk, ln_qk_b, bias_qk, DIM, DQK);
    bias_reduce<<<dim3(2, 1024 / BKC), 256, 0, stream>>>(W_o, ln_o_b, bias_o, 1024, DIM);

    const int G = CB * NG;   // groups per chunk
    for (int b0 = 0; b0 < BB; b0 += CB) {
        const float* xc = x    + (size_t)b0 * NN * DIM;
        float* outc     = outp + (size_t)b0 * NN * DIM;
        int R = rowsC;

        // 1) LN of token-shifted x -> hat1
        ln_kernel<float, DIM, 1><<<R, 256, 0, stream>>>(xc, hat1);
        // 2) merged gemm: hq[.,0..2047]=h, hq[.,2048..2175]=qk_pre (both silu)
        gemm_mfma<<<dim3(NHQ / 128, R / 128), 256, 0, stream>>>(
            hat1, WT_hq, bias_hq, hq, R, NHQ, DIM, NHQ);
        // 3) hid + hidT = h + dwconv(h)
        dwconv_dual<<<dim3(HID / 64, NN / 64, CB), 256, 0, stream>>>(hq, dw_h, hid, hidT, rowsC, NHQ);
        // 4) qkb = qk_pre + dwconv(qk_pre)
        dwconv_res<bf16><<<dim3(DQK / 64, NN / 64, CB), 256, 0, stream>>>(
            hq + HID, dw_qk, nullptr, qkb, DQK, NHQ);
        // 5) qk affine
        qk_affine<<<R / 64, 256, 0, stream>>>(qkb, gamma, beta, quadq, quadk, linq, linkT, rowsC);
        // 6) quadratic scores -> P (bf16)
        attn_score_mfma<<<dim3(2, 2, G), 256, 0, stream>>>(quadq, quadk, P);
        // 7) linear attention kv -> linkvT [g][e][d] fp32
        linkv_mfma<<<dim3(1, HID / 128, G), 256, 0, stream>>>(hidT, linkT, linkvT, rowsC);
        // 8) exclusive cumsum over groups -> linkvb bf16
        cumsum_bf<<<(CB * DQK * HID) / 256, 256, 0, stream>>>(linkvT, linkvb);
        // 9) fused apply + gating -> outg
        attn_apply_mfma<<<dim3(16, G), 256, 0, stream>>>(P, hidT, linq, linkvb, hid, outg, rowsC);
        // 10) LN(outg) -> hat2
        ln_kernel_bf<1024><<<R, 256, 0, stream>>>(outg, hat2);
        // 11) fin_pre = silu(hat2 @ W_o' + bias_o')
        gemm_mfma<<<dim3(DIM / 128, R / 128), 256, 0, stream>>>(
            hat2, WT_o, bias_o, fin_pre, R, DIM, 1024, DIM);
        // 12) d_out(fp32) = x + fin_pre + dwconv(fin_pre)
        dwconv_res<float><<<dim3(DIM / 64, NN / 64, CB), 256, 0, stream>>>(
            fin_pre, dw_o, xc, outc, DIM, DIM);
    }
}